// Round 11
// baseline (191.008 us; speedup 1.0000x reference)
//
#include <hip/hip_runtime.h>
#include <hip/hip_bf16.h>
#include <math.h>

#define N_TOK 2048
#define H_DIM 768
#define E_NUM 64
#define I_DIM 256
#define TOPK 8
#define NPAIR (N_TOK * TOPK)

typedef __attribute__((ext_vector_type(8))) short short8;
typedef __attribute__((ext_vector_type(4))) float f32x4;

__device__ inline ushort f2bf(float f) {
  unsigned u = __builtin_bit_cast(unsigned, f);
  u += 0x7fffu + ((u >> 16) & 1u);
  return (ushort)(u >> 16);
}

__device__ inline unsigned pack2(float a, float b) {
  return (unsigned)f2bf(a) | ((unsigned)f2bf(b) << 16);
}

__device__ inline f32x4 mfma16(short8 a, short8 b, f32x4 c) {
  return __builtin_amdgcn_mfma_f32_16x16x32_bf16(a, b, c, 0, 0, 0);
}

__device__ __forceinline__ void gload_lds16(const ushort* g, ushort* l) {
  __builtin_amdgcn_global_load_lds(
      (const __attribute__((address_space(1))) unsigned int*)g,
      (__attribute__((address_space(3))) unsigned int*)l, 16, 0, 0);
}

// ---------------- x fp32 -> bf16 ----------------
__global__ __launch_bounds__(512) void cvt_x_kernel(const float* __restrict__ x,
                                                    ushort* __restrict__ xbf) {
  const int i = blockIdx.x * 512 + threadIdx.x;
  const float* s = x + (size_t)i * 8;
  short8 r;
  #pragma unroll
  for (int j = 0; j < 8; ++j) r[j] = (short)f2bf(s[j]);
  *(short8*)(xbf + (size_t)i * 8) = r;
}

// ---------------- Weights: transpose + fp32->bf16, once per launch ---------
// wg/wu [e][768][256] -> [e][256][768]; wd [e][256][768] -> [e][768][256]
// Block = 64 input rows x 256 input cols. Every wave-instruction reads ONE
// FULL contiguous 1 KB row (lane l -> bytes l*16 of the row); consecutive
// rows per block -> 64 KB contiguous streams (DRAM row-buffer friendly).
// LDS transpose: write t2[rowpair][col] as ds_write_b128 (lanes 0-7 span all
// 32 banks -> conflict-free); read scalar columns at stride 260 (bank =
// (4*rp + c) % 32 -> conflict-free). Output bit-identical to prior rounds.
__global__ __launch_bounds__(256) void cvt_w_kernel(const float* __restrict__ wg,
                                                    const float* __restrict__ wu,
                                                    const float* __restrict__ wd,
                                                    ushort* __restrict__ wgbf,
                                                    ushort* __restrict__ wubf,
                                                    ushort* __restrict__ wdbf) {
  const int e = blockIdx.z, m = blockIdx.y, bx = blockIdx.x;
  const float* src;
  ushort* dst;
  int C, row0, col0, OR_;
  if (m < 2) {
    C = I_DIM;
    src = (m ? wu : wg) + (size_t)e * H_DIM * I_DIM;
    dst = (m ? wubf : wgbf) + (size_t)e * H_DIM * I_DIM;
    row0 = bx * 64; col0 = 0; OR_ = H_DIM;   // out [256][768]
  } else {
    C = H_DIM;
    src = wd + (size_t)e * I_DIM * H_DIM;
    dst = wdbf + (size_t)e * I_DIM * H_DIM;
    row0 = (bx & 3) * 64; col0 = (bx >> 2) * 256; OR_ = I_DIM;  // out [768][256]
  }
  __shared__ unsigned t2[32][260];  // [local row-pair][col], stride 260 u32
  const int tid = threadIdx.x, w = tid >> 6, l = tid & 63;
  #pragma unroll
  for (int j = 0; j < 4; ++j) {
    const float* rbase = src + (size_t)(row0 + j * 16 + w * 4) * C + col0 + l * 4;
    float4 v0 = *(const float4*)(rbase);
    float4 v1 = *(const float4*)(rbase + C);
    float4 v2 = *(const float4*)(rbase + 2 * C);
    float4 v3 = *(const float4*)(rbase + 3 * C);
    uint4 u01 = make_uint4(pack2(v0.x, v1.x), pack2(v0.y, v1.y),
                           pack2(v0.z, v1.z), pack2(v0.w, v1.w));
    uint4 u23 = make_uint4(pack2(v2.x, v3.x), pack2(v2.y, v3.y),
                           pack2(v2.z, v3.z), pack2(v2.w, v3.w));
    const int rp = j * 8 + w * 2;
    *(uint4*)&t2[rp][4 * l] = u01;
    *(uint4*)&t2[rp + 1][4 * l] = u23;
  }
  __syncthreads();
  const int c2 = tid;
  unsigned u[32];
  #pragma unroll
  for (int rp = 0; rp < 32; ++rp) u[rp] = t2[rp][c2];
  ushort* d = dst + (size_t)(col0 + c2) * OR_ + row0;
  #pragma unroll
  for (int s = 0; s < 8; ++s)
    *(uint4*)(d + s * 8) = make_uint4(u[4 * s], u[4 * s + 1], u[4 * s + 2], u[4 * s + 3]);
}

// ---------------- Router GEMM (fp32, split-K): part[ks][t][e] --------------
#define RT_KC 256
__global__ __launch_bounds__(256) void router_gemm(const float* __restrict__ x,
                                                   const float* __restrict__ rw,
                                                   float* __restrict__ part) {
  const int t0 = blockIdx.x * 64, k0 = blockIdx.y * RT_KC;
  __shared__ float xs[64][68];
  __shared__ float ws[64][68];
  const int tid = threadIdx.x;
  const int tx = tid & 15, ty = tid >> 4;
  float acc[4][4] = {};
  for (int kc = 0; kc < RT_KC; kc += 64) {
    __syncthreads();
    {
      const int r = tid >> 2, q = tid & 3;
      const float4* srcx = (const float4*)&x[(size_t)(t0 + r) * H_DIM + k0 + kc];
      const float4* srcw = (const float4*)&rw[(size_t)r * H_DIM + k0 + kc];
      float4* dstx = (float4*)&xs[r][0];
      float4* dstw = (float4*)&ws[r][0];
      #pragma unroll
      for (int j = 0; j < 4; ++j) {
        dstx[q * 4 + j] = srcx[q * 4 + j];
        dstw[q * 4 + j] = srcw[q * 4 + j];
      }
    }
    __syncthreads();
    #pragma unroll
    for (int k4 = 0; k4 < 16; ++k4) {
      float4 a0 = *(float4*)&xs[ty * 4 + 0][k4 * 4];
      float4 a1 = *(float4*)&xs[ty * 4 + 1][k4 * 4];
      float4 a2 = *(float4*)&xs[ty * 4 + 2][k4 * 4];
      float4 a3 = *(float4*)&xs[ty * 4 + 3][k4 * 4];
      float4 b0 = *(float4*)&ws[tx * 4 + 0][k4 * 4];
      float4 b1 = *(float4*)&ws[tx * 4 + 1][k4 * 4];
      float4 b2 = *(float4*)&ws[tx * 4 + 2][k4 * 4];
      float4 b3 = *(float4*)&ws[tx * 4 + 3][k4 * 4];
      #define RFMA(i, j, av, bv) \
        acc[i][j] = fmaf(av.x, bv.x, fmaf(av.y, bv.y, fmaf(av.z, bv.z, fmaf(av.w, bv.w, acc[i][j]))))
      RFMA(0, 0, a0, b0); RFMA(0, 1, a0, b1); RFMA(0, 2, a0, b2); RFMA(0, 3, a0, b3);
      RFMA(1, 0, a1, b0); RFMA(1, 1, a1, b1); RFMA(1, 2, a1, b2); RFMA(1, 3, a1, b3);
      RFMA(2, 0, a2, b0); RFMA(2, 1, a2, b1); RFMA(2, 2, a2, b2); RFMA(2, 3, a2, b3);
      RFMA(3, 0, a3, b0); RFMA(3, 1, a3, b1); RFMA(3, 2, a3, b2); RFMA(3, 3, a3, b3);
      #undef RFMA
    }
  }
  float* pp = part + ((size_t)blockIdx.y * N_TOK + t0) * E_NUM;
  #pragma unroll
  for (int i = 0; i < 4; ++i)
    #pragma unroll
    for (int j = 0; j < 4; ++j)
      pp[(ty * 4 + i) * E_NUM + tx * 4 + j] = acc[i][j];
}

// ---------------- Router top-k: sum partials -> top8 -> renorm -------------
__global__ __launch_bounds__(256) void router_topk(const float* __restrict__ part,
                                                   int* __restrict__ topi,
                                                   float* __restrict__ topw) {
  const int t = blockIdx.x * 4 + (threadIdx.x >> 6);
  const int l = threadIdx.x & 63;
  float myv = part[(size_t)t * E_NUM + l] +
              part[((size_t)N_TOK + t) * E_NUM + l] +
              part[((size_t)2 * N_TOK + t) * E_NUM + l];
  float topv[TOPK]; int topx[TOPK];
  #pragma unroll
  for (int k = 0; k < TOPK; ++k) {
    float bv = myv; int bi = l;
    #pragma unroll
    for (int off = 32; off > 0; off >>= 1) {
      float ov = __shfl_xor(bv, off, 64);
      int oi = __shfl_xor(bi, off, 64);
      if (ov > bv || (ov == bv && oi < bi)) { bv = ov; bi = oi; }
    }
    topv[k] = bv; topx[k] = bi;
    if (l == bi) myv = -INFINITY;
  }
  if (l == 0) {
    float mx = topv[0], w[TOPK], s = 0.f;
    #pragma unroll
    for (int k = 0; k < TOPK; ++k) { w[k] = __expf(topv[k] - mx); s += w[k]; }
    float inv = 1.f / s;
    #pragma unroll
    for (int k = 0; k < TOPK; ++k) {
      topi[t * TOPK + k] = topx[k];
      topw[t * TOPK + k] = w[k] * inv;
    }
  }
}

// ---------------- Histogram (LDS atomics) + prefix, single block -----------
__global__ __launch_bounds__(256) void hist_prefix_kernel(const int* __restrict__ topi,
                                                          int* __restrict__ offsets) {
  __shared__ int h[E_NUM];
  const int tid = threadIdx.x;
  if (tid < E_NUM) h[tid] = 0;
  __syncthreads();
  for (int i = tid; i < NPAIR; i += 256) atomicAdd(&h[topi[i]], 1);
  __syncthreads();
  if (tid == 0) {
    int s = 0;
    for (int e = 0; e < E_NUM; ++e) { offsets[e] = s; s += h[e]; }
    offsets[E_NUM] = s;
  }
}

// ---------------- Scatter: one block per expert, ordered ballot compaction -
__global__ __launch_bounds__(256) void scatter64(const int* __restrict__ topi,
                                                 const float* __restrict__ topw,
                                                 const int* __restrict__ offsets,
                                                 int* __restrict__ toklist,
                                                 float* __restrict__ wlist,
                                                 int* __restrict__ pairpos) {
  const int e = blockIdx.x;
  const int tid = threadIdx.x, l = tid & 63, w = tid >> 6;
  __shared__ int wcnt[4];
  __shared__ int base;
  if (tid == 0) base = offsets[e];
  __syncthreads();
  for (int c = 0; c < NPAIR; c += 256) {
    const int idx = c + tid;
    const bool p = (topi[idx] == e);
    const unsigned long long m = __ballot(p);
    if (l == 0) wcnt[w] = __popcll(m);
    __syncthreads();
    int off = base;
    for (int ww = 0; ww < 4; ++ww)
      if (ww < w) off += wcnt[ww];
    if (p) {
      const int pos = off + __popcll(m & ((1ull << l) - 1ull));
      toklist[pos] = idx >> 3;
      wlist[pos] = topw[idx];
      pairpos[idx] = pos;
    }
    __syncthreads();
    if (tid == 0) base += wcnt[0] + wcnt[1] + wcnt[2] + wcnt[3];
    __syncthreads();
  }
}

// ---------------- K1 (bf16 weights): all-DMA staging, SwiGLU in-register ---
#define NCH1 12
__global__ __launch_bounds__(512) void k1_gateup_bf(const ushort* __restrict__ xbf,
                                                    const ushort* __restrict__ wgbf,
                                                    const ushort* __restrict__ wubf,
                                                    const int* __restrict__ offsets,
                                                    const int* __restrict__ toklist,
                                                    ushort* __restrict__ hmid) {
  const int e = blockIdx.y, ib = blockIdx.x;
  const int i0 = ib * 64;
  const int start = offsets[e], cnt = offsets[e + 1] - start;
  const int tokbase = blockIdx.z * 128;
  if (tokbase >= cnt) return;
  const int cntb = min(128, cnt - tokbase);

  __shared__ __align__(16) ushort xs[2][128][64];
  __shared__ __align__(16) ushort Bs[2][128][64];
  __shared__ int tks[128];

  const int tid = threadIdx.x;
  if (tid < 128)
    tks[tid] = toklist[start + tokbase + min(tid, cntb - 1)];
  __syncthreads();

  const int l = tid & 63, wid = tid >> 6;
  const int tf = wid & 3, icw = wid >> 2;
  const int la15 = l & 15;
  const int lxor = (l & 7) ^ ((l >> 3) & 7);

  const int r0 = 16 * wid + (l >> 3);
  const ushort* srcx0 = xbf + (size_t)tks[r0] * H_DIM + lxor * 8;
  const ushort* srcx1 = xbf + (size_t)tks[r0 + 8] * H_DIM + lxor * 8;
  const int cB = 8 * wid + (l >> 3);
  const ushort* srcg = wgbf + (size_t)(e * I_DIM + i0 + cB) * H_DIM + lxor * 8;
  const ushort* srcu = wubf + (size_t)(e * I_DIM + i0 + cB) * H_DIM + lxor * 8;

  f32x4 accg[2][2] = {};
  f32x4 accu[2][2] = {};
  const int ra0 = tf * 32 + la15;
  const int cg0 = icw * 32 + la15;

  gload_lds16(srcx0, &xs[0][16 * wid][0]);
  gload_lds16(srcx1, &xs[0][16 * wid + 8][0]);
  gload_lds16(srcg, &Bs[0][8 * wid][0]);
  gload_lds16(srcu, &Bs[0][64 + 8 * wid][0]);
  asm volatile("s_waitcnt vmcnt(0) lgkmcnt(0)" ::: "memory");
  __builtin_amdgcn_sched_barrier(0);
  __builtin_amdgcn_s_barrier();

  for (int n = 0; n < NCH1; ++n) {
    const int cur = n & 1, nxt = cur ^ 1;
    const int khD = ((n + 1) % NCH1) * 64;
    gload_lds16(srcx0 + khD, &xs[nxt][16 * wid][0]);
    gload_lds16(srcx1 + khD, &xs[nxt][16 * wid + 8][0]);
    gload_lds16(srcg + khD, &Bs[nxt][8 * wid][0]);
    gload_lds16(srcu + khD, &Bs[nxt][64 + 8 * wid][0]);
    #pragma unroll
    for (int ks = 0; ks < 2; ++ks) {
      const int p8 = ((ks * 4 + (l >> 4)) ^ (l & 7)) * 8;
      short8 a0 = *(const short8*)&xs[cur][ra0][p8];
      short8 a1 = *(const short8*)&xs[cur][ra0 + 16][p8];
      short8 bg0 = *(const short8*)&Bs[cur][cg0][p8];
      short8 bg1 = *(const short8*)&Bs[cur][cg0 + 16][p8];
      short8 bu0 = *(const short8*)&Bs[cur][64 + cg0][p8];
      short8 bu1 = *(const short8*)&Bs[cur][64 + cg0 + 16][p8];
      __builtin_amdgcn_s_setprio(1);
      accg[0][0] = mfma16(a0, bg0, accg[0][0]);
      accg[0][1] = mfma16(a0, bg1, accg[0][1]);
      accg[1][0] = mfma16(a1, bg0, accg[1][0]);
      accg[1][1] = mfma16(a1, bg1, accg[1][1]);
      accu[0][0] = mfma16(a0, bu0, accu[0][0]);
      accu[0][1] = mfma16(a0, bu1, accu[0][1]);
      accu[1][0] = mfma16(a1, bu0, accu[1][0]);
      accu[1][1] = mfma16(a1, bu1, accu[1][1]);
      __builtin_amdgcn_s_setprio(0);
    }
    asm volatile("s_waitcnt vmcnt(0) lgkmcnt(0)" ::: "memory");
    __builtin_amdgcn_sched_barrier(0);
    __builtin_amdgcn_s_barrier();
  }

  ushort* tbuf = &xs[0][0][0];  // reuse as [128][72]
  #pragma unroll
  for (int r = 0; r < 2; ++r)
    #pragma unroll
    for (int c = 0; c < 2; ++c)
      #pragma unroll
      for (int jj = 0; jj < 4; ++jj) {
        const int row = tf * 32 + r * 16 + (l >> 4) * 4 + jj;
        const int col = icw * 32 + c * 16 + la15;
        float g = accg[r][c][jj];
        float hm = g / (1.f + __expf(-g)) * accu[r][c][jj];
        tbuf[row * 72 + col] = f2bf(hm);
      }
  __syncthreads();
  {
    const int row = tid >> 2, cs = tid & 3;
    if (row < cntb) {
      short8 v0 = *(const short8*)&tbuf[row * 72 + cs * 16];
      short8 v1 = *(const short8*)&tbuf[row * 72 + cs * 16 + 8];
      ushort* dst = hmid + (size_t)(start + tokbase + row) * I_DIM + i0 + cs * 16;
      *(short8*)dst = v0;
      *(short8*)(dst + 8) = v1;
    }
  }
}

// ---------------- K2 (bf16 weights): DMA-staged down-proj -> out_pairs -----
__global__ __launch_bounds__(512) void k2_down_bf(const ushort* __restrict__ hmid,
                                                  const ushort* __restrict__ wdbf,
                                                  const int* __restrict__ offsets,
                                                  float* __restrict__ out_pairs) {
  const int e = blockIdx.y, hs = blockIdx.x;
  const int h0 = hs * 192;
  const int start = offsets[e], cnt = offsets[e + 1] - start;
  const int tokbase = blockIdx.z * 128;
  if (tokbase >= cnt) return;
  const int tm = min(128, cnt - tokbase);

  __shared__ __align__(16) ushort Ds[2][192][64];

  const int tid = threadIdx.x, l = tid & 63, wid = tid >> 6;
  const int tf = wid & 3, ch = wid >> 2;
  const int la15 = l & 15;
  const int lxor = (l & 7) ^ ((l >> 3) & 7);
  f32x4 acc[2][6] = {};

  const int p0 = min(start + tokbase + tf * 32 + la15, NPAIR - 1);
  const int p1 = min(start + tokbase + tf * 32 + 16 + la15, NPAIR - 1);
  const int ko = (l >> 4) * 8;

  const int cB = 8 * wid + (l >> 3);
  const ushort* s0 = wdbf + (size_t)(e * H_DIM + h0 + cB) * I_DIM + lxor * 8;
  const ushort* s1 = s0 + (size_t)64 * I_DIM;
  const ushort* s2 = s0 + (size_t)128 * I_DIM;

  gload_lds16(s0, &Ds[0][8 * wid][0]);
  gload_lds16(s1, &Ds[0][64 + 8 * wid][0]);
  gload_lds16(s2, &Ds[0][128 + 8 * wid][0]);
  asm volatile("s_waitcnt vmcnt(0) lgkmcnt(0)" ::: "memory");
  __builtin_amdgcn_sched_barrier(0);
  __builtin_amdgcn_s_barrier();

  const ushort* ap0 = hmid + (size_t)p0 * I_DIM;
  const ushort* ap1 = hmid + (size_t)p1 * I_DIM;

  for (int n = 0; n < 4; ++n) {
    const int cur = n & 1, nxt = cur ^ 1;
    const int khD = ((n + 1) & 3) * 64;
    gload_lds16(s0 + khD, &Ds[nxt][8 * wid][0]);
    gload_lds16(s1 + khD, &Ds[nxt][64 + 8 * wid][0]);
    gload_lds16(s2 + khD, &Ds[nxt][128 + 8 * wid][0]);
    const int kh = n * 64;
    #pragma unroll
    for (int ks = 0; ks < 2; ++ks) {
      const int p8 = ((ks * 4 + (l >> 4)) ^ (l & 7)) * 8;
      short8 a0 = *(const short8*)(ap0 + kh + ks * 32 + ko);
      short8 a1 = *(const short8*)(ap1 + kh + ks * 32 + ko);
      __builtin_amdgcn_s_setprio(1);
      #pragma unroll
      for (int cf = 0; cf < 6; ++cf) {
        short8 b = *(const short8*)&Ds[cur][ch * 96 + cf * 16 + la15][p8];
        acc[0][cf] = mfma16(a0, b, acc[0][cf]);
        acc[1][cf] = mfma16(a1, b, acc[1][cf]);
      }
      __builtin_amdgcn_s_setprio(0);
    }
    asm volatile("s_waitcnt vmcnt(0) lgkmcnt(0)" ::: "memory");
    __builtin_amdgcn_sched_barrier(0);
    __builtin_amdgcn_s_barrier();
  }

  const int rgrp = l >> 4;
  #pragma unroll
  for (int tr = 0; tr < 2; ++tr)
    #pragma unroll
    for (int j = 0; j < 4; ++j) {
      int r = tf * 32 + tr * 16 + rgrp * 4 + j;
      if (r < tm) {
        const size_t prow = (size_t)(start + tokbase + r);
        #pragma unroll
        for (int cf = 0; cf < 6; ++cf) {
          int hcol = h0 + ch * 96 + cf * 16 + la15;
          out_pairs[prow * H_DIM + hcol] = acc[tr][cf][j];
        }
      }
    }
}

// ---------------- Fallback K1 (fp32 weights) --------------------------------
#define K1_TB 128
#define KC1 64
#define NCH 12
__global__ __launch_bounds__(512) void k1_gateup_fb(const ushort* __restrict__ xbf,
                                                    const float* __restrict__ wg,
                                                    const float* __restrict__ wu,
                                                    const int* __restrict__ offsets,
                                                    const int* __restrict__ toklist,
                                                    ushort* __restrict__ hmid) {
  const int e = blockIdx.y, ib = blockIdx.x;
  const int i0 = ib * 64;
  const int start = offsets[e], cnt = offsets[e + 1] - start;
  const int tokbase = blockIdx.z * K1_TB;
  if (tokbase >= cnt) return;
  const int cntb = min(K1_TB, cnt - tokbase);

  __shared__ __align__(16) ushort xs[2][K1_TB][64];
  __shared__ __align__(16) ushort Bs[2][128][72];
  __shared__ int tks[K1_TB];

  const int tid = threadIdx.x;
  if (tid < K1_TB)
    tks[tid] = toklist[start + tokbase + min(tid, cntb - 1)];
  __syncthreads();

  const int l = tid & 63, wid = tid >> 6;
  const int tf = wid & 3, icw = wid >> 2;

  const int seg = (l & 7) ^ ((l >> 3) & 7);
  const int r0 = 16 * wid + (l >> 3);
  const ushort* srcb0 = xbf + (size_t)tks[r0] * H_DIM + seg * 8;
  const ushort* srcb1 = xbf + (size_t)tks[r0 + 8] * H_DIM + seg * 8;

  const int q = tid & 31, km = tid >> 5;
  const int k0 = 2 * km;
  const float* wsrc = (q < 16 ? wg : wu) + (size_t)e * H_DIM * I_DIM + i0 + 4 * (q & 15);

  f32x4 accg[2][2] = {};
  f32x4 accu[2][2] = {};
  const int ko = (l >> 4) * 8;
  const int la15 = l & 15;
  const int ra0 = tf * 32 + la15;
  const int rx = ra0 & 7;

  float4 bv0 = *(const float4*)(wsrc + (size_t)(k0)*I_DIM);
  float4 bv1 = *(const float4*)(wsrc + (size_t)(k0 + 1) * I_DIM);
  float4 bv2 = *(const float4*)(wsrc + (size_t)(k0 + 32) * I_DIM);
  float4 bv3 = *(const float4*)(wsrc + (size_t)(k0 + 33) * I_DIM);
  gload_lds16(srcb0, &xs[0][16 * wid][0]);
  gload_lds16(srcb1, &xs[0][16 * wid + 8][0]);
  {
    *(unsigned*)&Bs[0][q * 4 + 0][k0] = pack2(bv0.x, bv1.x);
    *(unsigned*)&Bs[0][q * 4 + 1][k0] = pack2(bv0.y, bv1.y);
    *(unsigned*)&Bs[0][q * 4 + 2][k0] = pack2(bv0.z, bv1.z);
    *(unsigned*)&Bs[0][q * 4 + 3][k0] = pack2(bv0.w, bv1.w);
    *(unsigned*)&Bs[0][q * 4 + 0][k0 + 32] = pack2(bv2.x, bv3.x);
    *(unsigned*)&Bs[0][q * 4 + 1][k0 + 32] = pack2(bv2.y, bv3.y);
    *(unsigned*)&Bs[0][q * 4 + 2][k0 + 32] = pack2(bv2.z, bv3.z);
    *(unsigned*)&Bs[0][q * 4 + 3][k0 + 32] = pack2(bv2.w, bv3.w);
  }
  bv0 = *(const float4*)(wsrc + (size_t)(KC1 + k0) * I_DIM);
  bv1 = *(const float4*)(wsrc + (size_t)(KC1 + k0 + 1) * I_DIM);
  bv2 = *(const float4*)(wsrc + (size_t)(KC1 + k0 + 32) * I_DIM);
  bv3 = *(const float4*)(wsrc + (size_t)(KC1 + k0 + 33) * I_DIM);
  asm volatile("s_waitcnt vmcnt(4) lgkmcnt(0)" ::: "memory");
  __builtin_amdgcn_sched_barrier(0);
  __builtin_amdgcn_s_barrier();

  for (int n = 0; n < NCH; ++n) {
    const int cur = n & 1, nxt = cur ^ 1;
    const int khD = ((n + 1) % NCH) * KC1;
    gload_lds16(srcb0 + khD, &xs[nxt][16 * wid][0]);
    gload_lds16(srcb1 + khD, &xs[nxt][16 * wid + 8][0]);
    *(unsigned*)&Bs[nxt][q * 4 + 0][k0] = pack2(bv0.x, bv1.x);
    *(unsigned*)&Bs[nxt][q * 4 + 1][k0] = pack2(bv0.y, bv1.y);
    *(unsigned*)&Bs[nxt][q * 4 + 2][k0] = pack2(bv0.z, bv1.z);
    *(unsigned*)&Bs[nxt][q * 4 + 3][k0] = pack2(bv0.w, bv1.w);
    *(unsigned*)&Bs[nxt][q * 4 + 0][k0 + 32] = pack2(bv2.x, bv3.x);
    *(unsigned*)&Bs[nxt][q * 4 + 1][k0 + 32] = pack2(bv2.y, bv3.y);
    *(unsigned*)&Bs[nxt][q * 4 + 2][k0 + 32] = pack2(bv2.z, bv3.z);
    *(unsigned*)&Bs[nxt][q * 4 + 3][k0 + 32] = pack2(bv2.w, bv3.w);
    const int khB = ((n + 2) % NCH) * KC1;
    bv0 = *(const float4*)(wsrc + (size_t)(khB + k0) * I_DIM);
    bv1 = *(const float4*)(wsrc + (size_t)(khB + k0 + 1) * I_DIM);
    bv2 = *(const float4*)(wsrc + (size_t)(khB + k0 + 32) * I_DIM);
    bv3 = *(const float4*)(wsrc + (size_t)(khB + k0 + 33) * I_DIM);
    #pragma unroll
    for (int ks = 0; ks < 2; ++ks) {
      const int kof = ks * 32 + ko;
      const int sg = (ks * 4 + (l >> 4)) ^ rx;
      short8 a0 = *(const short8*)&xs[cur][ra0][sg * 8];
      short8 a1 = *(const short8*)&xs[cur][ra0 + 16][sg * 8];
      short8 bg0 = *(const short8*)&Bs[cur][icw * 32 + la15][kof];
      short8 bg1 = *(const short8*)&Bs[cur][icw * 32 + 16 + la15][kof];
      short8 bu0 = *(const short8*)&Bs[cur][64 + icw * 32 + la15][kof];
      short8 bu1 = *(const short8*)&Bs[cur][64 + icw * 32 + 16 + la15][kof];
      __builtin_amdgcn_s_setprio(1);
      accg[0][0] = mfma16(a0, bg0, accg[0][0]);
      accg[0][1] = mfma16(a0, bg1, accg[0][1]);
      accg[1][0] = mfma16(a1, bg0, accg[1][0]);
      accg[1][1] = mfma16(a1, bg1, accg[1][1]);
      accu[0][0] = mfma16(a0, bu0, accu[0][0]);
      accu[0][1] = mfma16(a0, bu1, accu[0][1]);
      accu[1][0] = mfma16(a1, bu0, accu[1][0]);
      accu[1][1] = mfma16(a1, bu1, accu[1][1]);
      __builtin_amdgcn_s_setprio(0);
    }
    asm volatile("s_waitcnt vmcnt(4) lgkmcnt(0)" ::: "memory");
    __builtin_amdgcn_sched_barrier(0);
    __builtin_amdgcn_s_barrier();
  }

  asm volatile("s_waitcnt vmcnt(0) lgkmcnt(0)" ::: "memory");
  __builtin_amdgcn_s_barrier();
  ushort* tbuf = &xs[0][0][0];
  #pragma unroll
  for (int r = 0; r < 2; ++r)
    #pragma unroll
    for (int c = 0; c < 2; ++c)
      #pragma unroll
      for (int jj = 0; jj < 4; ++jj) {
        const int row = tf * 32 + r * 16 + (l >> 4) * 4 + jj;
        const int col = icw * 32 + c * 16 + la15;
        float g = accg[r][c][jj];
        float hm = g / (1.f + __expf(-g)) * accu[r][c][jj];
        tbuf[row * 72 + col] = f2bf(hm);
      }
  __syncthreads();
  {
    const int row = tid >> 2, cs = tid & 3;
    if (row < cntb) {
      short8 v0 = *(const short8*)&tbuf[row * 72 + cs * 16];
      short8 v1 = *(const short8*)&tbuf[row * 72 + cs * 16 + 8];
      ushort* dst = hmid + (size_t)(start + tokbase + row) * I_DIM + i0 + cs * 16;
      *(short8*)dst = v0;
      *(short8*)(dst + 8) = v1;
    }
  }
}

// ---------------- Fallback K2 (fp32 weights) -> out_pairs --------------------
#define KC2 128
#define DS_S 136
__global__ __launch_bounds__(512) void k2_down_pairs_fb(const ushort* __restrict__ hmid,
                                                        const float* __restrict__ wd,
                                                        const int* __restrict__ offsets,
                                                        float* __restrict__ out_pairs) {
  const int e = blockIdx.y, hs = blockIdx.x;
  const int h0 = hs * 192;
  const int start = offsets[e], cnt = offsets[e + 1] - start;
  const int tokbase = blockIdx.z * 128;
  if (tokbase >= cnt) return;
  const int tm = min(128, cnt - tokbase);

  __shared__ ushort Ds[192][DS_S];

  const int tid = threadIdx.x;
  const int l = tid & 63, wid = tid >> 6;
  const int tf = wid & 3, ch = wid >> 2;
  f32x4 acc[2][6] = {};

  const int p0 = min(start + tokbase + tf * 32 + (l & 15), NPAIR - 1);
  const int p1 = min(start + tokbase + tf * 32 + 16 + (l & 15), NPAIR - 1);
  const int ko = (l >> 4) * 8;

  const float* wde = wd + (size_t)e * I_DIM * H_DIM;

  for (int kh = 0; kh < I_DIM; kh += KC2) {
    __syncthreads();
    #pragma unroll
    for (int it = 0; it < 6; ++it) {
      int idx = tid + it * 512;
      int q = idx % 48, m = idx / 48;
      const int k0 = 2 * m;
      const float* src = wde + (size_t)(kh + k0) * H_DIM + h0 + q * 4;
      float4 v0 = *(const float4*)src;
      float4 v1 = *(const float4*)(src + H_DIM);
      *(unsigned*)&Ds[q * 4 + 0][k0] = pack2(v0.x, v1.x);
      *(unsigned*)&Ds[q * 4 + 1][k0] = pack2(v0.y, v1.y);
      *(unsigned*)&Ds[q * 4 + 2][k0] = pack2(v0.z, v1.z);
      *(unsigned*)&Ds[q * 4 + 3][k0] = pack2(v0.w, v1.w);
    }
    __syncthreads();
    const ushort* ap0 = hmid + (size_t)p0 * I_DIM + kh;
    const ushort* ap1 = hmid + (size_t)p1 * I_DIM + kh;
    #pragma unroll
    for (int ks = 0; ks < KC2 / 32; ++ks) {
      short8 a0 = *(const short8*)(ap0 + ks * 32 + ko);
      short8 a1 = *(const short8*)(ap1 + ks * 32 + ko);
      #pragma unroll
      for (int cf = 0; cf < 6; ++cf) {
        short8 b = *(const short8*)&Ds[ch * 96 + cf * 16 + (l & 15)][ks * 32 + ko];
        acc[0][cf] = mfma16(a0, b, acc[0][cf]);
        acc[1][cf] = mfma16(a1, b, acc[1][cf]);
      }
    }
  }

  const int rgrp = l >> 4, col_l = l & 15;
  #pragma unroll
  for (int tr = 0; tr < 2; ++tr)
    #pragma unroll
    for (int j = 0; j < 4; ++j) {
      int r = tf * 32 + tr * 16 + rgrp * 4 + j;
      if (r < tm) {
        const size_t prow = (size_t)(start + tokbase + r);
        #pragma unroll
        for (int cf = 0; cf < 6; ++cf) {
          int hcol = h0 + ch * 96 + cf * 16 + col_l;
          out_pairs[prow * H_DIM + hcol] = acc[tr][cf][j];
        }
      }
    }
}

// ---------------- Gather-reduce: out[t] = sum_k w_k * out_pairs[pos(t,k)] --
__global__ __launch_bounds__(192) void moe_reduce(const float* __restrict__ out_pairs,
                                                  const int* __restrict__ pairpos,
                                                  const float* __restrict__ topw,
                                                  float* __restrict__ out) {
  const int t = blockIdx.x;
  const int c = threadIdx.x;
  float4 acc = make_float4(0.f, 0.f, 0.f, 0.f);
  #pragma unroll
  for (int k = 0; k < TOPK; ++k) {
    const int pos = pairpos[t * TOPK + k];
    const float w = topw[t * TOPK + k];
    float4 v = *(const float4*)&out_pairs[(size_t)pos * H_DIM + c * 4];
    acc.x = fmaf(w, v.x, acc.x);
    acc.y = fmaf(w, v.y, acc.y);
    acc.z = fmaf(w, v.z, acc.z);
    acc.w = fmaf(w, v.w, acc.w);
  }
  *(float4*)&out[(size_t)t * H_DIM + c * 4] = acc;
}

extern "C" void kernel_launch(void* const* d_in, const int* in_sizes, int n_in,
                              void* d_out, int out_size, void* d_ws, size_t ws_size,
                              hipStream_t stream) {
  const float* x  = (const float*)d_in[0];
  const float* rw = (const float*)d_in[1];
  const float* wg = (const float*)d_in[2];
  const float* wu = (const float*)d_in[3];
  const float* wd = (const float*)d_in[4];
  float* out = (float*)d_out;

  char* ws = (char*)d_ws;
  int*    topi     = (int*)(ws + 0);
  float*  topw     = (float*)(ws + 65536);
  int*    offsets  = (int*)(ws + 131072);
  int*    toklist  = (int*)(ws + 132608);
  float*  wlist    = (float*)(ws + 198144);
  int*    pairpos  = (int*)(ws + 264192);
  ushort* xbf      = (ushort*)(ws + 331776);   // 3 MB
  ushort* hmid     = (ushort*)(ws + 3477504);  // 8 MB
  float*  rpart    = (float*)(ws + 3477504);   // overlaps hmid; dead before k1
  float*  out_pairs= (float*)(ws + 11866112);  // 50.3 MB (k2 phase)
  ushort* wgbf     = (ushort*)(ws + 11866112); // 25.2 MB (k1 phase)
  ushort* wubf     = (ushort*)(ws + 37031936); // 25.2 MB
  ushort* wdbf     = (ushort*)(ws + 62197760); // 25.2 MB -> ends 87,363,584
  const bool fast2 = ws_size >= 87363584ull;

  cvt_x_kernel<<<(N_TOK * H_DIM / 8) / 512, 512, 0, stream>>>(x, xbf);
  if (fast2)
    cvt_w_kernel<<<dim3(12, 3, E_NUM), 256, 0, stream>>>(wg, wu, wd, wgbf, wubf, wdbf);
  router_gemm<<<dim3(N_TOK / 64, 3), 256, 0, stream>>>(x, rw, rpart);
  router_topk<<<N_TOK / 4, 256, 0, stream>>>(rpart, topi, topw);
  hist_prefix_kernel<<<1, 256, 0, stream>>>(topi, offsets);
  scatter64<<<E_NUM, 256, 0, stream>>>(topi, topw, offsets, toklist, wlist, pairpos);
  if (fast2) {
    k1_gateup_bf<<<dim3(4, E_NUM, 16), 512, 0, stream>>>(
        xbf, wgbf, wubf, offsets, toklist, hmid);
    k2_down_bf<<<dim3(4, E_NUM, 16), 512, 0, stream>>>(hmid, wdbf, offsets, out_pairs);
  } else {
    k1_gateup_fb<<<dim3(4, E_NUM, 16), 512, 0, stream>>>(
        xbf, wg, wu, offsets, toklist, hmid);
    k2_down_pairs_fb<<<dim3(4, E_NUM, 16), 512, 0, stream>>>(hmid, wd, offsets, out_pairs);
  }
  moe_reduce<<<N_TOK, 192, 0, stream>>>(out_pairs, pairpos, topw, out);
}

// Round 13
// 160.267 us; speedup vs baseline: 1.1918x; 1.1918x over previous
//
#include <hip/hip_runtime.h>
#include <hip/hip_bf16.h>
#include <math.h>

#define N_TOK 2048
#define H_DIM 768
#define E_NUM 64
#define I_DIM 256
#define TOPK 8
#define NPAIR (N_TOK * TOPK)

typedef __attribute__((ext_vector_type(8))) short short8;
typedef __attribute__((ext_vector_type(4))) float f32x4;

__device__ inline ushort f2bf(float f) {
  unsigned u = __builtin_bit_cast(unsigned, f);
  u += 0x7fffu + ((u >> 16) & 1u);
  return (ushort)(u >> 16);
}

__device__ inline unsigned pack2(float a, float b) {
  return (unsigned)f2bf(a) | ((unsigned)f2bf(b) << 16);
}

__device__ inline f32x4 mfma16(short8 a, short8 b, f32x4 c) {
  return __builtin_amdgcn_mfma_f32_16x16x32_bf16(a, b, c, 0, 0, 0);
}

__device__ __forceinline__ void gload_lds16(const ushort* g, ushort* l) {
  __builtin_amdgcn_global_load_lds(
      (const __attribute__((address_space(1))) unsigned int*)g,
      (__attribute__((address_space(3))) unsigned int*)l, 16, 0, 0);
}

// ---------------- x fp32 -> bf16 ----------------
__global__ __launch_bounds__(512) void cvt_x_kernel(const float* __restrict__ x,
                                                    ushort* __restrict__ xbf) {
  const int i = blockIdx.x * 512 + threadIdx.x;
  const float* s = x + (size_t)i * 8;
  short8 r;
  #pragma unroll
  for (int j = 0; j < 8; ++j) r[j] = (short)f2bf(s[j]);
  *(short8*)(xbf + (size_t)i * 8) = r;
}

// ---------------- Router GEMM (fp32, split-K): part[ks][t][e] --------------
#define RT_KC 256
__global__ __launch_bounds__(256) void router_gemm(const float* __restrict__ x,
                                                   const float* __restrict__ rw,
                                                   float* __restrict__ part) {
  const int t0 = blockIdx.x * 64, k0 = blockIdx.y * RT_KC;
  __shared__ float xs[64][68];
  __shared__ float ws[64][68];
  const int tid = threadIdx.x;
  const int tx = tid & 15, ty = tid >> 4;
  float acc[4][4] = {};
  for (int kc = 0; kc < RT_KC; kc += 64) {
    __syncthreads();
    {
      const int r = tid >> 2, q = tid & 3;
      const float4* srcx = (const float4*)&x[(size_t)(t0 + r) * H_DIM + k0 + kc];
      const float4* srcw = (const float4*)&rw[(size_t)r * H_DIM + k0 + kc];
      float4* dstx = (float4*)&xs[r][0];
      float4* dstw = (float4*)&ws[r][0];
      #pragma unroll
      for (int j = 0; j < 4; ++j) {
        dstx[q * 4 + j] = srcx[q * 4 + j];
        dstw[q * 4 + j] = srcw[q * 4 + j];
      }
    }
    __syncthreads();
    #pragma unroll
    for (int k4 = 0; k4 < 16; ++k4) {
      float4 a0 = *(float4*)&xs[ty * 4 + 0][k4 * 4];
      float4 a1 = *(float4*)&xs[ty * 4 + 1][k4 * 4];
      float4 a2 = *(float4*)&xs[ty * 4 + 2][k4 * 4];
      float4 a3 = *(float4*)&xs[ty * 4 + 3][k4 * 4];
      float4 b0 = *(float4*)&ws[tx * 4 + 0][k4 * 4];
      float4 b1 = *(float4*)&ws[tx * 4 + 1][k4 * 4];
      float4 b2 = *(float4*)&ws[tx * 4 + 2][k4 * 4];
      float4 b3 = *(float4*)&ws[tx * 4 + 3][k4 * 4];
      #define RFMA(i, j, av, bv) \
        acc[i][j] = fmaf(av.x, bv.x, fmaf(av.y, bv.y, fmaf(av.z, bv.z, fmaf(av.w, bv.w, acc[i][j]))))
      RFMA(0, 0, a0, b0); RFMA(0, 1, a0, b1); RFMA(0, 2, a0, b2); RFMA(0, 3, a0, b3);
      RFMA(1, 0, a1, b0); RFMA(1, 1, a1, b1); RFMA(1, 2, a1, b2); RFMA(1, 3, a1, b3);
      RFMA(2, 0, a2, b0); RFMA(2, 1, a2, b1); RFMA(2, 2, a2, b2); RFMA(2, 3, a2, b3);
      RFMA(3, 0, a3, b0); RFMA(3, 1, a3, b1); RFMA(3, 2, a3, b2); RFMA(3, 3, a3, b3);
      #undef RFMA
    }
  }
  float* pp = part + ((size_t)blockIdx.y * N_TOK + t0) * E_NUM;
  #pragma unroll
  for (int i = 0; i < 4; ++i)
    #pragma unroll
    for (int j = 0; j < 4; ++j)
      pp[(ty * 4 + i) * E_NUM + tx * 4 + j] = acc[i][j];
}

// ---------------- Router top-k: sum partials -> top8 -> renorm -------------
__global__ __launch_bounds__(256) void router_topk(const float* __restrict__ part,
                                                   int* __restrict__ topi,
                                                   float* __restrict__ topw) {
  const int t = blockIdx.x * 4 + (threadIdx.x >> 6);
  const int l = threadIdx.x & 63;
  float myv = part[(size_t)t * E_NUM + l] +
              part[((size_t)N_TOK + t) * E_NUM + l] +
              part[((size_t)2 * N_TOK + t) * E_NUM + l];
  float topv[TOPK]; int topx[TOPK];
  #pragma unroll
  for (int k = 0; k < TOPK; ++k) {
    float bv = myv; int bi = l;
    #pragma unroll
    for (int off = 32; off > 0; off >>= 1) {
      float ov = __shfl_xor(bv, off, 64);
      int oi = __shfl_xor(bi, off, 64);
      if (ov > bv || (ov == bv && oi < bi)) { bv = ov; bi = oi; }
    }
    topv[k] = bv; topx[k] = bi;
    if (l == bi) myv = -INFINITY;
  }
  if (l == 0) {
    float mx = topv[0], w[TOPK], s = 0.f;
    #pragma unroll
    for (int k = 0; k < TOPK; ++k) { w[k] = __expf(topv[k] - mx); s += w[k]; }
    float inv = 1.f / s;
    #pragma unroll
    for (int k = 0; k < TOPK; ++k) {
      topi[t * TOPK + k] = topx[k];
      topw[t * TOPK + k] = w[k] * inv;
    }
  }
}

// ---------------- Histogram (LDS atomics) + prefix, single block -----------
__global__ __launch_bounds__(256) void hist_prefix_kernel(const int* __restrict__ topi,
                                                          int* __restrict__ offsets) {
  __shared__ int h[E_NUM];
  const int tid = threadIdx.x;
  if (tid < E_NUM) h[tid] = 0;
  __syncthreads();
  for (int i = tid; i < NPAIR; i += 256) atomicAdd(&h[topi[i]], 1);
  __syncthreads();
  if (tid == 0) {
    int s = 0;
    for (int e = 0; e < E_NUM; ++e) { offsets[e] = s; s += h[e]; }
    offsets[E_NUM] = s;
  }
}

// ---------------- Scatter: one block per expert, ordered ballot compaction -
__global__ __launch_bounds__(256) void scatter64(const int* __restrict__ topi,
                                                 const float* __restrict__ topw,
                                                 const int* __restrict__ offsets,
                                                 int* __restrict__ toklist,
                                                 int* __restrict__ pairpos) {
  const int e = blockIdx.x;
  const int tid = threadIdx.x, l = tid & 63, w = tid >> 6;
  __shared__ int wcnt[4];
  __shared__ int base;
  if (tid == 0) base = offsets[e];
  __syncthreads();
  for (int c = 0; c < NPAIR; c += 256) {
    const int idx = c + tid;
    const bool p = (topi[idx] == e);
    const unsigned long long m = __ballot(p);
    if (l == 0) wcnt[w] = __popcll(m);
    __syncthreads();
    int off = base;
    for (int ww = 0; ww < 4; ++ww)
      if (ww < w) off += wcnt[ww];
    if (p) {
      const int pos = off + __popcll(m & ((1ull << l) - 1ull));
      toklist[pos] = idx >> 3;
      pairpos[idx] = pos;
    }
    __syncthreads();
    if (tid == 0) base += wcnt[0] + wcnt[1] + wcnt[2] + wcnt[3];
    __syncthreads();
  }
}

// ---------------- K1: fused fp32-weight gate/up MFMA + SwiGLU -> hmid ------
// block = (i-block of 64 cols, expert, 384-token tile); 8 waves = 4 row-bands
// x 2 col-halves; weights read ONCE per block, reg-staged 1 chunk ahead,
// transposed into Bs with stride-74 ushorts (37 u32, coprime-5 banks: <=2-way
// free). x via global_load_lds DMA (XOR-seg swizzle, R8-validated).
#define K1_TB 384
#define KC1 64
#define NCH1 12
#define BS_ST 74
__global__ __launch_bounds__(512) void k1_gateup(const ushort* __restrict__ xbf,
                                                 const float* __restrict__ wg,
                                                 const float* __restrict__ wu,
                                                 const int* __restrict__ offsets,
                                                 const int* __restrict__ toklist,
                                                 ushort* __restrict__ hmid) {
  const int e = blockIdx.y, ib = blockIdx.x;
  const int i0 = ib * 64;
  const int start = offsets[e], cnt = offsets[e + 1] - start;
  const int tokbase = blockIdx.z * K1_TB;
  if (tokbase >= cnt) return;
  const int cntb = min(K1_TB, cnt - tokbase);

  __shared__ __align__(16) ushort xs[2][K1_TB][64];  // 98304 B
  __shared__ __align__(16) ushort Bs[128][BS_ST];    // 18944 B (0-63 gate, 64-127 up)
  __shared__ int tks[K1_TB];                         // 1536 B

  const int tid = threadIdx.x;
  if (tid < K1_TB) tks[tid] = toklist[start + tokbase + min(tid, cntb - 1)];
  __syncthreads();

  const int l = tid & 63, wid = tid >> 6;
  const int tf = wid & 3, icw = wid >> 2;
  const int la15 = l & 15;
  const int lxor = (l & 7) ^ ((l >> 3) & 7);

  // x DMA sources: 6 groups of 8 rows per wave (48 rows/wave)
  const ushort* srcx0 = xbf + (size_t)tks[48 * wid + 0 + (l >> 3)] * H_DIM + lxor * 8;
  const ushort* srcx1 = xbf + (size_t)tks[48 * wid + 8 + (l >> 3)] * H_DIM + lxor * 8;
  const ushort* srcx2 = xbf + (size_t)tks[48 * wid + 16 + (l >> 3)] * H_DIM + lxor * 8;
  const ushort* srcx3 = xbf + (size_t)tks[48 * wid + 24 + (l >> 3)] * H_DIM + lxor * 8;
  const ushort* srcx4 = xbf + (size_t)tks[48 * wid + 32 + (l >> 3)] * H_DIM + lxor * 8;
  const ushort* srcx5 = xbf + (size_t)tks[48 * wid + 40 + (l >> 3)] * H_DIM + lxor * 8;

  // weight staging role: col-quad q (4 cols), k-pair kp
  const int q = tid & 15, kp = tid >> 4;  // kp 0..31
  const float* wgp = wg + (size_t)e * H_DIM * I_DIM + i0 + 4 * q;
  const float* wup = wu + (size_t)e * H_DIM * I_DIM + i0 + 4 * q;

  f32x4 accg[6][2] = {};
  f32x4 accu[6][2] = {};
  const int ko = (l >> 4) * 8;

  // prologue: wloads(0) FIRST (oldest), then DMA(0)
  float4 g0 = *(const float4*)(wgp + (size_t)(2 * kp) * I_DIM);
  float4 g1 = *(const float4*)(wgp + (size_t)(2 * kp + 1) * I_DIM);
  float4 u0 = *(const float4*)(wup + (size_t)(2 * kp) * I_DIM);
  float4 u1 = *(const float4*)(wup + (size_t)(2 * kp + 1) * I_DIM);
  gload_lds16(srcx0, &xs[0][48 * wid + 0][0]);
  gload_lds16(srcx1, &xs[0][48 * wid + 8][0]);
  gload_lds16(srcx2, &xs[0][48 * wid + 16][0]);
  gload_lds16(srcx3, &xs[0][48 * wid + 24][0]);
  gload_lds16(srcx4, &xs[0][48 * wid + 32][0]);
  gload_lds16(srcx5, &xs[0][48 * wid + 40][0]);

  for (int n = 0; n < NCH1; ++n) {
    const int cur = n & 1, nxt = cur ^ 1;
    // (A) write Bs(n) from regs (compiler auto-waits wload(n) only)
    *(unsigned*)&Bs[q * 4 + 0][2 * kp] = pack2(g0.x, g1.x);
    *(unsigned*)&Bs[q * 4 + 1][2 * kp] = pack2(g0.y, g1.y);
    *(unsigned*)&Bs[q * 4 + 2][2 * kp] = pack2(g0.z, g1.z);
    *(unsigned*)&Bs[q * 4 + 3][2 * kp] = pack2(g0.w, g1.w);
    *(unsigned*)&Bs[64 + q * 4 + 0][2 * kp] = pack2(u0.x, u1.x);
    *(unsigned*)&Bs[64 + q * 4 + 1][2 * kp] = pack2(u0.y, u1.y);
    *(unsigned*)&Bs[64 + q * 4 + 2][2 * kp] = pack2(u0.z, u1.z);
    *(unsigned*)&Bs[64 + q * 4 + 3][2 * kp] = pack2(u0.w, u1.w);
    if (n + 1 < NCH1) {
      const int kh = (n + 1) * KC1;
      // (B) wloads(n+1) — stay in flight across the barrier
      g0 = *(const float4*)(wgp + (size_t)(kh + 2 * kp) * I_DIM);
      g1 = *(const float4*)(wgp + (size_t)(kh + 2 * kp + 1) * I_DIM);
      u0 = *(const float4*)(wup + (size_t)(kh + 2 * kp) * I_DIM);
      u1 = *(const float4*)(wup + (size_t)(kh + 2 * kp + 1) * I_DIM);
      // (C) DMA x(n+1)
      gload_lds16(srcx0 + kh, &xs[nxt][48 * wid + 0][0]);
      gload_lds16(srcx1 + kh, &xs[nxt][48 * wid + 8][0]);
      gload_lds16(srcx2 + kh, &xs[nxt][48 * wid + 16][0]);
      gload_lds16(srcx3 + kh, &xs[nxt][48 * wid + 24][0]);
      gload_lds16(srcx4 + kh, &xs[nxt][48 * wid + 32][0]);
      gload_lds16(srcx5 + kh, &xs[nxt][48 * wid + 40][0]);
      // (D) drain DMA(n) (oldest 6 of 16 in flight), keep wloads+DMA(n+1)
      asm volatile("s_waitcnt vmcnt(10) lgkmcnt(0)" ::: "memory");
      __builtin_amdgcn_sched_barrier(0);
      __builtin_amdgcn_s_barrier();
    } else {
      asm volatile("s_waitcnt vmcnt(0) lgkmcnt(0)" ::: "memory");
      __builtin_amdgcn_sched_barrier(0);
      __builtin_amdgcn_s_barrier();
    }
    // (E) MFMA chunk n
    #pragma unroll
    for (int ks = 0; ks < 2; ++ks) {
      const int kof = ks * 32 + ko;
      const int sg8 = ((ks * 4 + (l >> 4)) ^ (l & 7)) * 8;
      short8 bg0 = *(const short8*)&Bs[icw * 32 + la15][kof];
      short8 bg1 = *(const short8*)&Bs[icw * 32 + 16 + la15][kof];
      short8 bu0 = *(const short8*)&Bs[64 + icw * 32 + la15][kof];
      short8 bu1 = *(const short8*)&Bs[64 + icw * 32 + 16 + la15][kof];
      __builtin_amdgcn_s_setprio(1);
      #pragma unroll
      for (int rf = 0; rf < 6; ++rf) {
        short8 a = *(const short8*)&xs[cur][tf * 96 + rf * 16 + la15][sg8];
        accg[rf][0] = mfma16(a, bg0, accg[rf][0]);
        accg[rf][1] = mfma16(a, bg1, accg[rf][1]);
        accu[rf][0] = mfma16(a, bu0, accu[rf][0]);
        accu[rf][1] = mfma16(a, bu1, accu[rf][1]);
      }
      __builtin_amdgcn_s_setprio(0);
    }
    // (F) barrier-2: all waves done reading xs[cur] and Bs(n)
    asm volatile("s_waitcnt lgkmcnt(0)" ::: "memory");
    __builtin_amdgcn_sched_barrier(0);
    __builtin_amdgcn_s_barrier();
  }

  // epilogue: in-register SwiGLU -> LDS transpose -> coalesced store
  ushort* tbuf = &xs[0][0][0];  // [384][72] = 55296 B; xs dead after loop
  #pragma unroll
  for (int rf = 0; rf < 6; ++rf)
    #pragma unroll
    for (int c = 0; c < 2; ++c)
      #pragma unroll
      for (int jj = 0; jj < 4; ++jj) {
        const int row = tf * 96 + rf * 16 + (l >> 4) * 4 + jj;
        const int col = icw * 32 + c * 16 + la15;
        float g = accg[rf][c][jj];
        float hm = g / (1.f + __expf(-g)) * accu[rf][c][jj];
        tbuf[row * 72 + col] = f2bf(hm);
      }
  __syncthreads();
  #pragma unroll
  for (int p = 0; p < 3; ++p) {
    const int row = (tid >> 2) + p * 128, cs = tid & 3;
    if (row < cntb) {
      short8 v0 = *(const short8*)&tbuf[row * 72 + cs * 16];
      short8 v1 = *(const short8*)&tbuf[row * 72 + cs * 16 + 8];
      ushort* dst = hmid + (size_t)(start + tokbase + row) * I_DIM + i0 + cs * 16;
      *(short8*)dst = v0;
      *(short8*)(dst + 8) = v1;
    }
  }
}

// ---------------- K2: fused fp32-weight down-proj -> out_pairs -------------
// block = (h-slice of 192, expert, 256-token tile); stride-138 Ds (69 u32,
// coprime-5 banks). Weights read ~once per block (z usually 1-2 live tiles).
#define K2_TB 256
#define KC2 128
#define DS_ST 138
__global__ __launch_bounds__(512) void k2_down(const ushort* __restrict__ hmid,
                                               const float* __restrict__ wd,
                                               const int* __restrict__ offsets,
                                               float* __restrict__ out_pairs) {
  const int e = blockIdx.y, hs = blockIdx.x;
  const int h0 = hs * 192;
  const int start = offsets[e], cnt = offsets[e + 1] - start;
  const int tokbase = blockIdx.z * K2_TB;
  if (tokbase >= cnt) return;
  const int tm = min(K2_TB, cnt - tokbase);

  __shared__ ushort Ds[192][DS_ST];  // 52992 B

  const int tid = threadIdx.x, l = tid & 63, wid = tid >> 6;
  const int tf = wid & 3, ch = wid >> 2;
  const int la15 = l & 15;
  const int ko = (l >> 4) * 8;
  f32x4 acc[4][6] = {};

  int p[4];
  #pragma unroll
  for (int rf = 0; rf < 4; ++rf)
    p[rf] = min(start + tokbase + tf * 64 + rf * 16 + la15, NPAIR - 1);

  const float* wde = wd + (size_t)e * I_DIM * H_DIM;

  for (int kh = 0; kh < I_DIM; kh += KC2) {
    __syncthreads();
    #pragma unroll
    for (int it = 0; it < 6; ++it) {
      int idx = tid + it * 512;
      int qq = idx % 48, m = idx / 48;  // m 0..63
      const int k0 = 2 * m;
      const float* src = wde + (size_t)(kh + k0) * H_DIM + h0 + qq * 4;
      float4 v0 = *(const float4*)src;
      float4 v1 = *(const float4*)(src + H_DIM);
      *(unsigned*)&Ds[qq * 4 + 0][k0] = pack2(v0.x, v1.x);
      *(unsigned*)&Ds[qq * 4 + 1][k0] = pack2(v0.y, v1.y);
      *(unsigned*)&Ds[qq * 4 + 2][k0] = pack2(v0.z, v1.z);
      *(unsigned*)&Ds[qq * 4 + 3][k0] = pack2(v0.w, v1.w);
    }
    __syncthreads();
    #pragma unroll
    for (int ks = 0; ks < 4; ++ks) {
      const int kof = ks * 32 + ko;
      short8 a[4];
      #pragma unroll
      for (int rf = 0; rf < 4; ++rf)
        a[rf] = *(const short8*)(hmid + (size_t)p[rf] * I_DIM + kh + kof);
      __builtin_amdgcn_s_setprio(1);
      #pragma unroll
      for (int cf = 0; cf < 6; ++cf) {
        short8 b = *(const short8*)&Ds[ch * 96 + cf * 16 + la15][kof];
        #pragma unroll
        for (int rf = 0; rf < 4; ++rf)
          acc[rf][cf] = mfma16(a[rf], b, acc[rf][cf]);
      }
      __builtin_amdgcn_s_setprio(0);
    }
  }

  const int rgrp = l >> 4;
  #pragma unroll
  for (int rf = 0; rf < 4; ++rf)
    #pragma unroll
    for (int jj = 0; jj < 4; ++jj) {
      int r = tf * 64 + rf * 16 + rgrp * 4 + jj;
      if (r < tm) {
        const size_t prow = (size_t)(start + tokbase + r);
        #pragma unroll
        for (int cf = 0; cf < 6; ++cf) {
          int hcol = h0 + ch * 96 + cf * 16 + la15;
          out_pairs[prow * H_DIM + hcol] = acc[rf][cf][jj];
        }
      }
    }
}

// ---------------- Gather-reduce: out[t] = sum_k w_k * out_pairs[pos(t,k)] --
__global__ __launch_bounds__(192) void moe_reduce(const float* __restrict__ out_pairs,
                                                  const int* __restrict__ pairpos,
                                                  const float* __restrict__ topw,
                                                  float* __restrict__ out) {
  const int t = blockIdx.x;
  const int c = threadIdx.x;
  float4 acc = make_float4(0.f, 0.f, 0.f, 0.f);
  #pragma unroll
  for (int k = 0; k < TOPK; ++k) {
    const int pos = pairpos[t * TOPK + k];
    const float w = topw[t * TOPK + k];
    float4 v = *(const float4*)&out_pairs[(size_t)pos * H_DIM + c * 4];
    acc.x = fmaf(w, v.x, acc.x);
    acc.y = fmaf(w, v.y, acc.y);
    acc.z = fmaf(w, v.z, acc.z);
    acc.w = fmaf(w, v.w, acc.w);
  }
  *(float4*)&out[(size_t)t * H_DIM + c * 4] = acc;
}

extern "C" void kernel_launch(void* const* d_in, const int* in_sizes, int n_in,
                              void* d_out, int out_size, void* d_ws, size_t ws_size,
                              hipStream_t stream) {
  const float* x  = (const float*)d_in[0];
  const float* rw = (const float*)d_in[1];
  const float* wg = (const float*)d_in[2];
  const float* wu = (const float*)d_in[3];
  const float* wd = (const float*)d_in[4];
  float* out = (float*)d_out;

  char* ws = (char*)d_ws;
  int*    topi     = (int*)(ws + 0);
  float*  topw     = (float*)(ws + 65536);
  int*    offsets  = (int*)(ws + 131072);
  int*    toklist  = (int*)(ws + 132608);
  int*    pairpos  = (int*)(ws + 264192);
  ushort* xbf      = (ushort*)(ws + 331776);   // 3 MB
  ushort* hmid     = (ushort*)(ws + 3477504);  // 8 MB
  float*  rpart    = (float*)(ws + 3477504);   // overlaps hmid; dead before k1
  float*  out_pairs= (float*)(ws + 11866112);  // 50.3 MB -> ends 62,197,760

  cvt_x_kernel<<<(N_TOK * H_DIM / 8) / 512, 512, 0, stream>>>(x, xbf);
  router_gemm<<<dim3(N_TOK / 64, 3), 256, 0, stream>>>(x, rw, rpart);
  router_topk<<<N_TOK / 4, 256, 0, stream>>>(rpart, topi, topw);
  hist_prefix_kernel<<<1, 256, 0, stream>>>(topi, offsets);
  scatter64<<<E_NUM, 256, 0, stream>>>(topi, topw, offsets, toklist, pairpos);
  // z-grids cover worst-case cnt == 2048: ceil(2048/384)=6, ceil(2048/256)=8
  k1_gateup<<<dim3(4, E_NUM, 6), 512, 0, stream>>>(xbf, wg, wu, offsets, toklist, hmid);
  k2_down<<<dim3(4, E_NUM, 8), 512, 0, stream>>>(hmid, wd, offsets, out_pairs);
  moe_reduce<<<N_TOK, 192, 0, stream>>>(out_pairs, pairpos, topw, out);
}

// Round 14
// 155.249 us; speedup vs baseline: 1.2303x; 1.0323x over previous
//
#include <hip/hip_runtime.h>
#include <hip/hip_bf16.h>
#include <math.h>

#define N_TOK 2048
#define H_DIM 768
#define E_NUM 64
#define I_DIM 256
#define TOPK 8
#define NPAIR (N_TOK * TOPK)

typedef __attribute__((ext_vector_type(8))) short short8;
typedef __attribute__((ext_vector_type(4))) float f32x4;

__device__ inline ushort f2bf(float f) {
  unsigned u = __builtin_bit_cast(unsigned, f);
  u += 0x7fffu + ((u >> 16) & 1u);
  return (ushort)(u >> 16);
}

__device__ inline unsigned pack2(float a, float b) {
  return (unsigned)f2bf(a) | ((unsigned)f2bf(b) << 16);
}

__device__ inline f32x4 mfma16(short8 a, short8 b, f32x4 c) {
  return __builtin_amdgcn_mfma_f32_16x16x32_bf16(a, b, c, 0, 0, 0);
}

__device__ __forceinline__ void gload_lds16(const ushort* g, ushort* l) {
  __builtin_amdgcn_global_load_lds(
      (const __attribute__((address_space(1))) unsigned int*)g,
      (__attribute__((address_space(3))) unsigned int*)l, 16, 0, 0);
}

// ---------------- x fp32 -> bf16 ----------------
__global__ __launch_bounds__(512) void cvt_x_kernel(const float* __restrict__ x,
                                                    ushort* __restrict__ xbf) {
  const int i = blockIdx.x * 512 + threadIdx.x;
  const float* s = x + (size_t)i * 8;
  short8 r;
  #pragma unroll
  for (int j = 0; j < 8; ++j) r[j] = (short)f2bf(s[j]);
  *(short8*)(xbf + (size_t)i * 8) = r;
}

// ---------------- Router GEMM (fp32, split-K): part[ks][t][e] --------------
#define RT_KC 256
__global__ __launch_bounds__(256) void router_gemm(const float* __restrict__ x,
                                                   const float* __restrict__ rw,
                                                   float* __restrict__ part) {
  const int t0 = blockIdx.x * 64, k0 = blockIdx.y * RT_KC;
  __shared__ float xs[64][68];
  __shared__ float ws[64][68];
  const int tid = threadIdx.x;
  const int tx = tid & 15, ty = tid >> 4;
  float acc[4][4] = {};
  for (int kc = 0; kc < RT_KC; kc += 64) {
    __syncthreads();
    {
      const int r = tid >> 2, q = tid & 3;
      const float4* srcx = (const float4*)&x[(size_t)(t0 + r) * H_DIM + k0 + kc];
      const float4* srcw = (const float4*)&rw[(size_t)r * H_DIM + k0 + kc];
      float4* dstx = (float4*)&xs[r][0];
      float4* dstw = (float4*)&ws[r][0];
      #pragma unroll
      for (int j = 0; j < 4; ++j) {
        dstx[q * 4 + j] = srcx[q * 4 + j];
        dstw[q * 4 + j] = srcw[q * 4 + j];
      }
    }
    __syncthreads();
    #pragma unroll
    for (int k4 = 0; k4 < 16; ++k4) {
      float4 a0 = *(float4*)&xs[ty * 4 + 0][k4 * 4];
      float4 a1 = *(float4*)&xs[ty * 4 + 1][k4 * 4];
      float4 a2 = *(float4*)&xs[ty * 4 + 2][k4 * 4];
      float4 a3 = *(float4*)&xs[ty * 4 + 3][k4 * 4];
      float4 b0 = *(float4*)&ws[tx * 4 + 0][k4 * 4];
      float4 b1 = *(float4*)&ws[tx * 4 + 1][k4 * 4];
      float4 b2 = *(float4*)&ws[tx * 4 + 2][k4 * 4];
      float4 b3 = *(float4*)&ws[tx * 4 + 3][k4 * 4];
      #define RFMA(i, j, av, bv) \
        acc[i][j] = fmaf(av.x, bv.x, fmaf(av.y, bv.y, fmaf(av.z, bv.z, fmaf(av.w, bv.w, acc[i][j]))))
      RFMA(0, 0, a0, b0); RFMA(0, 1, a0, b1); RFMA(0, 2, a0, b2); RFMA(0, 3, a0, b3);
      RFMA(1, 0, a1, b0); RFMA(1, 1, a1, b1); RFMA(1, 2, a1, b2); RFMA(1, 3, a1, b3);
      RFMA(2, 0, a2, b0); RFMA(2, 1, a2, b1); RFMA(2, 2, a2, b2); RFMA(2, 3, a2, b3);
      RFMA(3, 0, a3, b0); RFMA(3, 1, a3, b1); RFMA(3, 2, a3, b2); RFMA(3, 3, a3, b3);
      #undef RFMA
    }
  }
  float* pp = part + ((size_t)blockIdx.y * N_TOK + t0) * E_NUM;
  #pragma unroll
  for (int i = 0; i < 4; ++i)
    #pragma unroll
    for (int j = 0; j < 4; ++j)
      pp[(ty * 4 + i) * E_NUM + tx * 4 + j] = acc[i][j];
}

// ---------------- Router top-k: sum partials -> top8 -> renorm -------------
__global__ __launch_bounds__(256) void router_topk(const float* __restrict__ part,
                                                   int* __restrict__ topi,
                                                   float* __restrict__ topw) {
  const int t = blockIdx.x * 4 + (threadIdx.x >> 6);
  const int l = threadIdx.x & 63;
  float myv = part[(size_t)t * E_NUM + l] +
              part[((size_t)N_TOK + t) * E_NUM + l] +
              part[((size_t)2 * N_TOK + t) * E_NUM + l];
  float topv[TOPK]; int topx[TOPK];
  #pragma unroll
  for (int k = 0; k < TOPK; ++k) {
    float bv = myv; int bi = l;
    #pragma unroll
    for (int off = 32; off > 0; off >>= 1) {
      float ov = __shfl_xor(bv, off, 64);
      int oi = __shfl_xor(bi, off, 64);
      if (ov > bv || (ov == bv && oi < bi)) { bv = ov; bi = oi; }
    }
    topv[k] = bv; topx[k] = bi;
    if (l == bi) myv = -INFINITY;
  }
  if (l == 0) {
    float mx = topv[0], w[TOPK], s = 0.f;
    #pragma unroll
    for (int k = 0; k < TOPK; ++k) { w[k] = __expf(topv[k] - mx); s += w[k]; }
    float inv = 1.f / s;
    #pragma unroll
    for (int k = 0; k < TOPK; ++k) {
      topi[t * TOPK + k] = topx[k];
      topw[t * TOPK + k] = w[k] * inv;
    }
  }
}

// ---------------- Histogram (LDS atomics) + prefix, single block -----------
__global__ __launch_bounds__(256) void hist_prefix_kernel(const int* __restrict__ topi,
                                                          int* __restrict__ offsets) {
  __shared__ int h[E_NUM];
  const int tid = threadIdx.x;
  if (tid < E_NUM) h[tid] = 0;
  __syncthreads();
  for (int i = tid; i < NPAIR; i += 256) atomicAdd(&h[topi[i]], 1);
  __syncthreads();
  if (tid == 0) {
    int s = 0;
    for (int e = 0; e < E_NUM; ++e) { offsets[e] = s; s += h[e]; }
    offsets[E_NUM] = s;
  }
}

// ---------------- Scatter: one block per expert, ordered ballot compaction -
__global__ __launch_bounds__(256) void scatter64(const int* __restrict__ topi,
                                                 const float* __restrict__ topw,
                                                 const int* __restrict__ offsets,
                                                 int* __restrict__ toklist,
                                                 int* __restrict__ pairpos) {
  const int e = blockIdx.x;
  const int tid = threadIdx.x, l = tid & 63, w = tid >> 6;
  __shared__ int wcnt[4];
  __shared__ int base;
  if (tid == 0) base = offsets[e];
  __syncthreads();
  for (int c = 0; c < NPAIR; c += 256) {
    const int idx = c + tid;
    const bool p = (topi[idx] == e);
    const unsigned long long m = __ballot(p);
    if (l == 0) wcnt[w] = __popcll(m);
    __syncthreads();
    int off = base;
    for (int ww = 0; ww < 4; ++ww)
      if (ww < w) off += wcnt[ww];
    if (p) {
      const int pos = off + __popcll(m & ((1ull << l) - 1ull));
      toklist[pos] = idx >> 3;
      pairpos[idx] = pos;
    }
    __syncthreads();
    if (tid == 0) base += wcnt[0] + wcnt[1] + wcnt[2] + wcnt[3];
    __syncthreads();
  }
}

// ---------------- K1: fused fp32-weight gate/up MFMA + SwiGLU -> hmid ------
// block = (i-block of 64 cols, expert, 192-token tile); 8 waves = 4 row-bands
// x 2 col-halves. LDS 69 KB + launch_bounds(512,4) -> 2 blocks/CU so
// independent blocks hide each other's weight-load latency (m114).
// Weight re-reads by the 2nd token tile hit L3 (151 MB < 256 MB).
#define K1_TB 192
#define KC1 64
#define NCH1 12
#define BS_ST 74
__global__ __launch_bounds__(512, 4) void k1_gateup(const ushort* __restrict__ xbf,
                                                    const float* __restrict__ wg,
                                                    const float* __restrict__ wu,
                                                    const int* __restrict__ offsets,
                                                    const int* __restrict__ toklist,
                                                    ushort* __restrict__ hmid) {
  const int e = blockIdx.y, ib = blockIdx.x;
  const int i0 = ib * 64;
  const int start = offsets[e], cnt = offsets[e + 1] - start;
  const int tokbase = blockIdx.z * K1_TB;
  if (tokbase >= cnt) return;
  const int cntb = min(K1_TB, cnt - tokbase);

  __shared__ __align__(16) ushort xs[2][K1_TB][64];  // 49152 B
  __shared__ __align__(16) ushort Bs[128][BS_ST];    // 18944 B (0-63 gate, 64-127 up)
  __shared__ int tks[K1_TB];                         // 768 B

  const int tid = threadIdx.x;
  if (tid < K1_TB) tks[tid] = toklist[start + tokbase + min(tid, cntb - 1)];
  __syncthreads();

  const int l = tid & 63, wid = tid >> 6;
  const int tf = wid & 3, icw = wid >> 2;
  const int la15 = l & 15;
  const int lxor = (l & 7) ^ ((l >> 3) & 7);

  // x DMA sources: 3 groups of 8 rows per wave (24 rows/wave)
  const ushort* srcx0 = xbf + (size_t)tks[24 * wid + 0 + (l >> 3)] * H_DIM + lxor * 8;
  const ushort* srcx1 = xbf + (size_t)tks[24 * wid + 8 + (l >> 3)] * H_DIM + lxor * 8;
  const ushort* srcx2 = xbf + (size_t)tks[24 * wid + 16 + (l >> 3)] * H_DIM + lxor * 8;

  // weight staging role: col-quad q (4 cols), k-pair kp
  const int q = tid & 15, kp = tid >> 4;  // kp 0..31
  const float* wgp = wg + (size_t)e * H_DIM * I_DIM + i0 + 4 * q;
  const float* wup = wu + (size_t)e * H_DIM * I_DIM + i0 + 4 * q;

  f32x4 accg[3][2] = {};
  f32x4 accu[3][2] = {};
  const int ko = (l >> 4) * 8;

  // prologue: wloads(0) FIRST (oldest), then DMA(0)
  float4 g0 = *(const float4*)(wgp + (size_t)(2 * kp) * I_DIM);
  float4 g1 = *(const float4*)(wgp + (size_t)(2 * kp + 1) * I_DIM);
  float4 u0 = *(const float4*)(wup + (size_t)(2 * kp) * I_DIM);
  float4 u1 = *(const float4*)(wup + (size_t)(2 * kp + 1) * I_DIM);
  gload_lds16(srcx0, &xs[0][24 * wid + 0][0]);
  gload_lds16(srcx1, &xs[0][24 * wid + 8][0]);
  gload_lds16(srcx2, &xs[0][24 * wid + 16][0]);

  for (int n = 0; n < NCH1; ++n) {
    const int cur = n & 1, nxt = cur ^ 1;
    // (A) write Bs(n) from regs (compiler auto-waits wload(n) only)
    *(unsigned*)&Bs[q * 4 + 0][2 * kp] = pack2(g0.x, g1.x);
    *(unsigned*)&Bs[q * 4 + 1][2 * kp] = pack2(g0.y, g1.y);
    *(unsigned*)&Bs[q * 4 + 2][2 * kp] = pack2(g0.z, g1.z);
    *(unsigned*)&Bs[q * 4 + 3][2 * kp] = pack2(g0.w, g1.w);
    *(unsigned*)&Bs[64 + q * 4 + 0][2 * kp] = pack2(u0.x, u1.x);
    *(unsigned*)&Bs[64 + q * 4 + 1][2 * kp] = pack2(u0.y, u1.y);
    *(unsigned*)&Bs[64 + q * 4 + 2][2 * kp] = pack2(u0.z, u1.z);
    *(unsigned*)&Bs[64 + q * 4 + 3][2 * kp] = pack2(u0.w, u1.w);
    if (n + 1 < NCH1) {
      const int kh = (n + 1) * KC1;
      // (B) wloads(n+1) — stay in flight across the barrier
      g0 = *(const float4*)(wgp + (size_t)(kh + 2 * kp) * I_DIM);
      g1 = *(const float4*)(wgp + (size_t)(kh + 2 * kp + 1) * I_DIM);
      u0 = *(const float4*)(wup + (size_t)(kh + 2 * kp) * I_DIM);
      u1 = *(const float4*)(wup + (size_t)(kh + 2 * kp + 1) * I_DIM);
      // (C) DMA x(n+1)
      gload_lds16(srcx0 + kh, &xs[nxt][24 * wid + 0][0]);
      gload_lds16(srcx1 + kh, &xs[nxt][24 * wid + 8][0]);
      gload_lds16(srcx2 + kh, &xs[nxt][24 * wid + 16][0]);
      // (D) drain DMA(n) (oldest 3 of 10 in flight), keep wloads+DMA(n+1)
      asm volatile("s_waitcnt vmcnt(7) lgkmcnt(0)" ::: "memory");
      __builtin_amdgcn_sched_barrier(0);
      __builtin_amdgcn_s_barrier();
    } else {
      asm volatile("s_waitcnt vmcnt(0) lgkmcnt(0)" ::: "memory");
      __builtin_amdgcn_sched_barrier(0);
      __builtin_amdgcn_s_barrier();
    }
    // (E) MFMA chunk n
    #pragma unroll
    for (int ks = 0; ks < 2; ++ks) {
      const int kof = ks * 32 + ko;
      const int sg8 = ((ks * 4 + (l >> 4)) ^ (l & 7)) * 8;
      short8 bg0 = *(const short8*)&Bs[icw * 32 + la15][kof];
      short8 bg1 = *(const short8*)&Bs[icw * 32 + 16 + la15][kof];
      short8 bu0 = *(const short8*)&Bs[64 + icw * 32 + la15][kof];
      short8 bu1 = *(const short8*)&Bs[64 + icw * 32 + 16 + la15][kof];
      __builtin_amdgcn_s_setprio(1);
      #pragma unroll
      for (int rf = 0; rf < 3; ++rf) {
        short8 a = *(const short8*)&xs[cur][tf * 48 + rf * 16 + la15][sg8];
        accg[rf][0] = mfma16(a, bg0, accg[rf][0]);
        accg[rf][1] = mfma16(a, bg1, accg[rf][1]);
        accu[rf][0] = mfma16(a, bu0, accu[rf][0]);
        accu[rf][1] = mfma16(a, bu1, accu[rf][1]);
      }
      __builtin_amdgcn_s_setprio(0);
    }
    // (F) barrier-2: all waves done reading xs[cur] and Bs(n)
    asm volatile("s_waitcnt lgkmcnt(0)" ::: "memory");
    __builtin_amdgcn_sched_barrier(0);
    __builtin_amdgcn_s_barrier();
  }

  // epilogue: in-register SwiGLU -> LDS transpose -> coalesced store
  ushort* tbuf = &xs[0][0][0];  // [192][72] = 27648 B; xs dead after loop
  #pragma unroll
  for (int rf = 0; rf < 3; ++rf)
    #pragma unroll
    for (int c = 0; c < 2; ++c)
      #pragma unroll
      for (int jj = 0; jj < 4; ++jj) {
        const int row = tf * 48 + rf * 16 + (l >> 4) * 4 + jj;
        const int col = icw * 32 + c * 16 + la15;
        float g = accg[rf][c][jj];
        float hm = g / (1.f + __expf(-g)) * accu[rf][c][jj];
        tbuf[row * 72 + col] = f2bf(hm);
      }
  __syncthreads();
  #pragma unroll
  for (int p = 0; p < 2; ++p) {
    const int row = (tid >> 2) + p * 128, cs = tid & 3;
    if (row < cntb) {
      short8 v0 = *(const short8*)&tbuf[row * 72 + cs * 16];
      short8 v1 = *(const short8*)&tbuf[row * 72 + cs * 16 + 8];
      ushort* dst = hmid + (size_t)(start + tokbase + row) * I_DIM + i0 + cs * 16;
      *(short8*)dst = v0;
      *(short8*)(dst + 8) = v1;
    }
  }
}

// ---------------- K2: fused fp32-weight down-proj -> out_pairs -------------
#define K2_TB 256
#define KC2 128
#define DS_ST 138
__global__ __launch_bounds__(512) void k2_down(const ushort* __restrict__ hmid,
                                               const float* __restrict__ wd,
                                               const int* __restrict__ offsets,
                                               float* __restrict__ out_pairs) {
  const int e = blockIdx.y, hs = blockIdx.x;
  const int h0 = hs * 192;
  const int start = offsets[e], cnt = offsets[e + 1] - start;
  const int tokbase = blockIdx.z * K2_TB;
  if (tokbase >= cnt) return;
  const int tm = min(K2_TB, cnt - tokbase);

  __shared__ ushort Ds[192][DS_ST];  // 52992 B

  const int tid = threadIdx.x, l = tid & 63, wid = tid >> 6;
  const int tf = wid & 3, ch = wid >> 2;
  const int la15 = l & 15;
  const int ko = (l >> 4) * 8;
  f32x4 acc[4][6] = {};

  int p[4];
  #pragma unroll
  for (int rf = 0; rf < 4; ++rf)
    p[rf] = min(start + tokbase + tf * 64 + rf * 16 + la15, NPAIR - 1);

  const float* wde = wd + (size_t)e * I_DIM * H_DIM;

  for (int kh = 0; kh < I_DIM; kh += KC2) {
    __syncthreads();
    #pragma unroll
    for (int it = 0; it < 6; ++it) {
      int idx = tid + it * 512;
      int qq = idx % 48, m = idx / 48;  // m 0..63
      const int k0 = 2 * m;
      const float* src = wde + (size_t)(kh + k0) * H_DIM + h0 + qq * 4;
      float4 v0 = *(const float4*)src;
      float4 v1 = *(const float4*)(src + H_DIM);
      *(unsigned*)&Ds[qq * 4 + 0][k0] = pack2(v0.x, v1.x);
      *(unsigned*)&Ds[qq * 4 + 1][k0] = pack2(v0.y, v1.y);
      *(unsigned*)&Ds[qq * 4 + 2][k0] = pack2(v0.z, v1.z);
      *(unsigned*)&Ds[qq * 4 + 3][k0] = pack2(v0.w, v1.w);
    }
    __syncthreads();
    #pragma unroll
    for (int ks = 0; ks < 4; ++ks) {
      const int kof = ks * 32 + ko;
      short8 a[4];
      #pragma unroll
      for (int rf = 0; rf < 4; ++rf)
        a[rf] = *(const short8*)(hmid + (size_t)p[rf] * I_DIM + kh + kof);
      __builtin_amdgcn_s_setprio(1);
      #pragma unroll
      for (int cf = 0; cf < 6; ++cf) {
        short8 b = *(const short8*)&Ds[ch * 96 + cf * 16 + la15][kof];
        #pragma unroll
        for (int rf = 0; rf < 4; ++rf)
          acc[rf][cf] = mfma16(a[rf], b, acc[rf][cf]);
      }
      __builtin_amdgcn_s_setprio(0);
    }
  }

  const int rgrp = l >> 4;
  #pragma unroll
  for (int rf = 0; rf < 4; ++rf)
    #pragma unroll
    for (int jj = 0; jj < 4; ++jj) {
      int r = tf * 64 + rf * 16 + rgrp * 4 + jj;
      if (r < tm) {
        const size_t prow = (size_t)(start + tokbase + r);
        #pragma unroll
        for (int cf = 0; cf < 6; ++cf) {
          int hcol = h0 + ch * 96 + cf * 16 + la15;
          out_pairs[prow * H_DIM + hcol] = acc[rf][cf][jj];
        }
      }
    }
}

// ---------------- Gather-reduce: out[t] = sum_k w_k * out_pairs[pos(t,k)] --
__global__ __launch_bounds__(192) void moe_reduce(const float* __restrict__ out_pairs,
                                                  const int* __restrict__ pairpos,
                                                  const float* __restrict__ topw,
                                                  float* __restrict__ out) {
  const int t = blockIdx.x;
  const int c = threadIdx.x;
  float4 acc = make_float4(0.f, 0.f, 0.f, 0.f);
  #pragma unroll
  for (int k = 0; k < TOPK; ++k) {
    const int pos = pairpos[t * TOPK + k];
    const float w = topw[t * TOPK + k];
    float4 v = *(const float4*)&out_pairs[(size_t)pos * H_DIM + c * 4];
    acc.x = fmaf(w, v.x, acc.x);
    acc.y = fmaf(w, v.y, acc.y);
    acc.z = fmaf(w, v.z, acc.z);
    acc.w = fmaf(w, v.w, acc.w);
  }
  *(float4*)&out[(size_t)t * H_DIM + c * 4] = acc;
}

extern "C" void kernel_launch(void* const* d_in, const int* in_sizes, int n_in,
                              void* d_out, int out_size, void* d_ws, size_t ws_size,
                              hipStream_t stream) {
  const float* x  = (const float*)d_in[0];
  const float* rw = (const float*)d_in[1];
  const float* wg = (const float*)d_in[2];
  const float* wu = (const float*)d_in[3];
  const float* wd = (const float*)d_in[4];
  float* out = (float*)d_out;

  char* ws = (char*)d_ws;
  int*    topi     = (int*)(ws + 0);
  float*  topw     = (float*)(ws + 65536);
  int*    offsets  = (int*)(ws + 131072);
  int*    toklist  = (int*)(ws + 132608);
  int*    pairpos  = (int*)(ws + 264192);
  ushort* xbf      = (ushort*)(ws + 331776);   // 3 MB
  ushort* hmid     = (ushort*)(ws + 3477504);  // 8 MB
  float*  rpart    = (float*)(ws + 3477504);   // overlaps hmid; dead before k1
  float*  out_pairs= (float*)(ws + 11866112);  // 50.3 MB -> ends 62,197,760

  cvt_x_kernel<<<(N_TOK * H_DIM / 8) / 512, 512, 0, stream>>>(x, xbf);
  router_gemm<<<dim3(N_TOK / 64, 3), 256, 0, stream>>>(x, rw, rpart);
  router_topk<<<N_TOK / 4, 256, 0, stream>>>(rpart, topi, topw);
  hist_prefix_kernel<<<1, 256, 0, stream>>>(topi, offsets);
  scatter64<<<E_NUM, 256, 0, stream>>>(topi, topw, offsets, toklist, pairpos);
  // z-grids cover worst-case cnt == 2048: ceil(2048/192)=11, ceil(2048/256)=8
  k1_gateup<<<dim3(4, E_NUM, 11), 512, 0, stream>>>(xbf, wg, wu, offsets, toklist, hmid);
  k2_down<<<dim3(4, E_NUM, 8), 512, 0, stream>>>(hmid, wd, offsets, out_pairs);
  moe_reduce<<<N_TOK, 192, 0, stream>>>(out_pairs, pairpos, topw, out);
}

// Round 15
// 134.736 us; speedup vs baseline: 1.4176x; 1.1522x over previous
//
#include <hip/hip_runtime.h>
#include <hip/hip_bf16.h>
#include <math.h>

#define N_TOK 2048
#define H_DIM 768
#define E_NUM 64
#define I_DIM 256
#define TOPK 8
#define NPAIR (N_TOK * TOPK)

typedef __attribute__((ext_vector_type(8))) short short8;
typedef __attribute__((ext_vector_type(4))) short short4v;
typedef __attribute__((ext_vector_type(4))) float f32x4;

__device__ inline ushort f2bf(float f) {
  unsigned u = __builtin_bit_cast(unsigned, f);
  u += 0x7fffu + ((u >> 16) & 1u);
  return (ushort)(u >> 16);
}

__device__ inline float bf2f(ushort h) {
  return __builtin_bit_cast(float, (unsigned)h << 16);
}

__device__ inline unsigned pack2(float a, float b) {
  return (unsigned)f2bf(a) | ((unsigned)f2bf(b) << 16);
}

__device__ inline f32x4 mfma16(short8 a, short8 b, f32x4 c) {
  return __builtin_amdgcn_mfma_f32_16x16x32_bf16(a, b, c, 0, 0, 0);
}

__device__ __forceinline__ void gload_lds16(const ushort* g, ushort* l) {
  __builtin_amdgcn_global_load_lds(
      (const __attribute__((address_space(1))) unsigned int*)g,
      (__attribute__((address_space(3))) unsigned int*)l, 16, 0, 0);
}

// ---------------- x fp32 -> bf16 ----------------
__global__ __launch_bounds__(512) void cvt_x_kernel(const float* __restrict__ x,
                                                    ushort* __restrict__ xbf) {
  const int i = blockIdx.x * 512 + threadIdx.x;
  const float* s = x + (size_t)i * 8;
  short8 r;
  #pragma unroll
  for (int j = 0; j < 8; ++j) r[j] = (short)f2bf(s[j]);
  *(short8*)(xbf + (size_t)i * 8) = r;
}

// ---------------- Router GEMM (fp32, split-K): part[ks][t][e] --------------
#define RT_KC 256
__global__ __launch_bounds__(256) void router_gemm(const float* __restrict__ x,
                                                   const float* __restrict__ rw,
                                                   float* __restrict__ part) {
  const int t0 = blockIdx.x * 64, k0 = blockIdx.y * RT_KC;
  __shared__ float xs[64][68];
  __shared__ float ws[64][68];
  const int tid = threadIdx.x;
  const int tx = tid & 15, ty = tid >> 4;
  float acc[4][4] = {};
  for (int kc = 0; kc < RT_KC; kc += 64) {
    __syncthreads();
    {
      const int r = tid >> 2, q = tid & 3;
      const float4* srcx = (const float4*)&x[(size_t)(t0 + r) * H_DIM + k0 + kc];
      const float4* srcw = (const float4*)&rw[(size_t)r * H_DIM + k0 + kc];
      float4* dstx = (float4*)&xs[r][0];
      float4* dstw = (float4*)&ws[r][0];
      #pragma unroll
      for (int j = 0; j < 4; ++j) {
        dstx[q * 4 + j] = srcx[q * 4 + j];
        dstw[q * 4 + j] = srcw[q * 4 + j];
      }
    }
    __syncthreads();
    #pragma unroll
    for (int k4 = 0; k4 < 16; ++k4) {
      float4 a0 = *(float4*)&xs[ty * 4 + 0][k4 * 4];
      float4 a1 = *(float4*)&xs[ty * 4 + 1][k4 * 4];
      float4 a2 = *(float4*)&xs[ty * 4 + 2][k4 * 4];
      float4 a3 = *(float4*)&xs[ty * 4 + 3][k4 * 4];
      float4 b0 = *(float4*)&ws[tx * 4 + 0][k4 * 4];
      float4 b1 = *(float4*)&ws[tx * 4 + 1][k4 * 4];
      float4 b2 = *(float4*)&ws[tx * 4 + 2][k4 * 4];
      float4 b3 = *(float4*)&ws[tx * 4 + 3][k4 * 4];
      #define RFMA(i, j, av, bv) \
        acc[i][j] = fmaf(av.x, bv.x, fmaf(av.y, bv.y, fmaf(av.z, bv.z, fmaf(av.w, bv.w, acc[i][j]))))
      RFMA(0, 0, a0, b0); RFMA(0, 1, a0, b1); RFMA(0, 2, a0, b2); RFMA(0, 3, a0, b3);
      RFMA(1, 0, a1, b0); RFMA(1, 1, a1, b1); RFMA(1, 2, a1, b2); RFMA(1, 3, a1, b3);
      RFMA(2, 0, a2, b0); RFMA(2, 1, a2, b1); RFMA(2, 2, a2, b2); RFMA(2, 3, a2, b3);
      RFMA(3, 0, a3, b0); RFMA(3, 1, a3, b1); RFMA(3, 2, a3, b2); RFMA(3, 3, a3, b3);
      #undef RFMA
    }
  }
  float* pp = part + ((size_t)blockIdx.y * N_TOK + t0) * E_NUM;
  #pragma unroll
  for (int i = 0; i < 4; ++i)
    #pragma unroll
    for (int j = 0; j < 4; ++j)
      pp[(ty * 4 + i) * E_NUM + tx * 4 + j] = acc[i][j];
}

// ---------------- Router top-k: sum partials -> top8 -> renorm -------------
__global__ __launch_bounds__(256) void router_topk(const float* __restrict__ part,
                                                   int* __restrict__ topi,
                                                   float* __restrict__ topw) {
  const int t = blockIdx.x * 4 + (threadIdx.x >> 6);
  const int l = threadIdx.x & 63;
  float myv = part[(size_t)t * E_NUM + l] +
              part[((size_t)N_TOK + t) * E_NUM + l] +
              part[((size_t)2 * N_TOK + t) * E_NUM + l];
  float topv[TOPK]; int topx[TOPK];
  #pragma unroll
  for (int k = 0; k < TOPK; ++k) {
    float bv = myv; int bi = l;
    #pragma unroll
    for (int off = 32; off > 0; off >>= 1) {
      float ov = __shfl_xor(bv, off, 64);
      int oi = __shfl_xor(bi, off, 64);
      if (ov > bv || (ov == bv && oi < bi)) { bv = ov; bi = oi; }
    }
    topv[k] = bv; topx[k] = bi;
    if (l == bi) myv = -INFINITY;
  }
  if (l == 0) {
    float mx = topv[0], w[TOPK], s = 0.f;
    #pragma unroll
    for (int k = 0; k < TOPK; ++k) { w[k] = __expf(topv[k] - mx); s += w[k]; }
    float inv = 1.f / s;
    #pragma unroll
    for (int k = 0; k < TOPK; ++k) {
      topi[t * TOPK + k] = topx[k];
      topw[t * TOPK + k] = w[k] * inv;
    }
  }
}

// ---------------- Histogram (LDS atomics) + prefix, single block -----------
__global__ __launch_bounds__(256) void hist_prefix_kernel(const int* __restrict__ topi,
                                                          int* __restrict__ offsets) {
  __shared__ int h[E_NUM];
  const int tid = threadIdx.x;
  if (tid < E_NUM) h[tid] = 0;
  __syncthreads();
  for (int i = tid; i < NPAIR; i += 256) atomicAdd(&h[topi[i]], 1);
  __syncthreads();
  if (tid == 0) {
    int s = 0;
    for (int e = 0; e < E_NUM; ++e) { offsets[e] = s; s += h[e]; }
    offsets[E_NUM] = s;
  }
}

// ---------------- Scatter: two-pass per-wave ballot, ONE barrier -----------
// Wave w owns idx range [w*4096,(w+1)*4096). Order stays idx-ascending.
__global__ __launch_bounds__(256) void scatter64(const int* __restrict__ topi,
                                                 const int* __restrict__ offsets,
                                                 int* __restrict__ toklist,
                                                 int* __restrict__ pairpos) {
  const int e = blockIdx.x;
  const int tid = threadIdx.x, l = tid & 63, w = tid >> 6;
  __shared__ int wcnt[4];
  int cnt = 0;
  for (int c = 0; c < NPAIR / 4; c += 64) {
    const int idx = w * (NPAIR / 4) + c + l;
    cnt += __popcll(__ballot(topi[idx] == e));
  }
  if (l == 0) wcnt[w] = cnt;
  __syncthreads();
  int base = offsets[e];
  for (int ww = 0; ww < 4; ++ww)
    if (ww < w) base += wcnt[ww];
  for (int c = 0; c < NPAIR / 4; c += 64) {
    const int idx = w * (NPAIR / 4) + c + l;
    const bool p = (topi[idx] == e);
    const unsigned long long m = __ballot(p);
    if (p) {
      const int pos = base + __popcll(m & ((1ull << l) - 1ull));
      toklist[pos] = idx >> 3;
      pairpos[idx] = pos;
    }
    base += __popcll(m);
  }
}

// ---------------- K1: fused fp32-weight gate/up MFMA + SwiGLU -> hmid ------
// (unchanged from R14 passing kernel)
#define K1_TB 192
#define KC1 64
#define NCH1 12
#define BS_ST 74
__global__ __launch_bounds__(512, 4) void k1_gateup(const ushort* __restrict__ xbf,
                                                    const float* __restrict__ wg,
                                                    const float* __restrict__ wu,
                                                    const int* __restrict__ offsets,
                                                    const int* __restrict__ toklist,
                                                    ushort* __restrict__ hmid) {
  const int e = blockIdx.y, ib = blockIdx.x;
  const int i0 = ib * 64;
  const int start = offsets[e], cnt = offsets[e + 1] - start;
  const int tokbase = blockIdx.z * K1_TB;
  if (tokbase >= cnt) return;
  const int cntb = min(K1_TB, cnt - tokbase);

  __shared__ __align__(16) ushort xs[2][K1_TB][64];
  __shared__ __align__(16) ushort Bs[128][BS_ST];
  __shared__ int tks[K1_TB];

  const int tid = threadIdx.x;
  if (tid < K1_TB) tks[tid] = toklist[start + tokbase + min(tid, cntb - 1)];
  __syncthreads();

  const int l = tid & 63, wid = tid >> 6;
  const int tf = wid & 3, icw = wid >> 2;
  const int la15 = l & 15;
  const int lxor = (l & 7) ^ ((l >> 3) & 7);

  const ushort* srcx0 = xbf + (size_t)tks[24 * wid + 0 + (l >> 3)] * H_DIM + lxor * 8;
  const ushort* srcx1 = xbf + (size_t)tks[24 * wid + 8 + (l >> 3)] * H_DIM + lxor * 8;
  const ushort* srcx2 = xbf + (size_t)tks[24 * wid + 16 + (l >> 3)] * H_DIM + lxor * 8;

  const int q = tid & 15, kp = tid >> 4;
  const float* wgp = wg + (size_t)e * H_DIM * I_DIM + i0 + 4 * q;
  const float* wup = wu + (size_t)e * H_DIM * I_DIM + i0 + 4 * q;

  f32x4 accg[3][2] = {};
  f32x4 accu[3][2] = {};
  const int ko = (l >> 4) * 8;

  float4 g0 = *(const float4*)(wgp + (size_t)(2 * kp) * I_DIM);
  float4 g1 = *(const float4*)(wgp + (size_t)(2 * kp + 1) * I_DIM);
  float4 u0 = *(const float4*)(wup + (size_t)(2 * kp) * I_DIM);
  float4 u1 = *(const float4*)(wup + (size_t)(2 * kp + 1) * I_DIM);
  gload_lds16(srcx0, &xs[0][24 * wid + 0][0]);
  gload_lds16(srcx1, &xs[0][24 * wid + 8][0]);
  gload_lds16(srcx2, &xs[0][24 * wid + 16][0]);

  for (int n = 0; n < NCH1; ++n) {
    const int cur = n & 1, nxt = cur ^ 1;
    *(unsigned*)&Bs[q * 4 + 0][2 * kp] = pack2(g0.x, g1.x);
    *(unsigned*)&Bs[q * 4 + 1][2 * kp] = pack2(g0.y, g1.y);
    *(unsigned*)&Bs[q * 4 + 2][2 * kp] = pack2(g0.z, g1.z);
    *(unsigned*)&Bs[q * 4 + 3][2 * kp] = pack2(g0.w, g1.w);
    *(unsigned*)&Bs[64 + q * 4 + 0][2 * kp] = pack2(u0.x, u1.x);
    *(unsigned*)&Bs[64 + q * 4 + 1][2 * kp] = pack2(u0.y, u1.y);
    *(unsigned*)&Bs[64 + q * 4 + 2][2 * kp] = pack2(u0.z, u1.z);
    *(unsigned*)&Bs[64 + q * 4 + 3][2 * kp] = pack2(u0.w, u1.w);
    if (n + 1 < NCH1) {
      const int kh = (n + 1) * KC1;
      g0 = *(const float4*)(wgp + (size_t)(kh + 2 * kp) * I_DIM);
      g1 = *(const float4*)(wgp + (size_t)(kh + 2 * kp + 1) * I_DIM);
      u0 = *(const float4*)(wup + (size_t)(kh + 2 * kp) * I_DIM);
      u1 = *(const float4*)(wup + (size_t)(kh + 2 * kp + 1) * I_DIM);
      gload_lds16(srcx0 + kh, &xs[nxt][24 * wid + 0][0]);
      gload_lds16(srcx1 + kh, &xs[nxt][24 * wid + 8][0]);
      gload_lds16(srcx2 + kh, &xs[nxt][24 * wid + 16][0]);
      asm volatile("s_waitcnt vmcnt(7) lgkmcnt(0)" ::: "memory");
      __builtin_amdgcn_sched_barrier(0);
      __builtin_amdgcn_s_barrier();
    } else {
      asm volatile("s_waitcnt vmcnt(0) lgkmcnt(0)" ::: "memory");
      __builtin_amdgcn_sched_barrier(0);
      __builtin_amdgcn_s_barrier();
    }
    #pragma unroll
    for (int ks = 0; ks < 2; ++ks) {
      const int kof = ks * 32 + ko;
      const int sg8 = ((ks * 4 + (l >> 4)) ^ (l & 7)) * 8;
      short8 bg0 = *(const short8*)&Bs[icw * 32 + la15][kof];
      short8 bg1 = *(const short8*)&Bs[icw * 32 + 16 + la15][kof];
      short8 bu0 = *(const short8*)&Bs[64 + icw * 32 + la15][kof];
      short8 bu1 = *(const short8*)&Bs[64 + icw * 32 + 16 + la15][kof];
      __builtin_amdgcn_s_setprio(1);
      #pragma unroll
      for (int rf = 0; rf < 3; ++rf) {
        short8 a = *(const short8*)&xs[cur][tf * 48 + rf * 16 + la15][sg8];
        accg[rf][0] = mfma16(a, bg0, accg[rf][0]);
        accg[rf][1] = mfma16(a, bg1, accg[rf][1]);
        accu[rf][0] = mfma16(a, bu0, accu[rf][0]);
        accu[rf][1] = mfma16(a, bu1, accu[rf][1]);
      }
      __builtin_amdgcn_s_setprio(0);
    }
    asm volatile("s_waitcnt lgkmcnt(0)" ::: "memory");
    __builtin_amdgcn_sched_barrier(0);
    __builtin_amdgcn_s_barrier();
  }

  ushort* tbuf = &xs[0][0][0];
  #pragma unroll
  for (int rf = 0; rf < 3; ++rf)
    #pragma unroll
    for (int c = 0; c < 2; ++c)
      #pragma unroll
      for (int jj = 0; jj < 4; ++jj) {
        const int row = tf * 48 + rf * 16 + (l >> 4) * 4 + jj;
        const int col = icw * 32 + c * 16 + la15;
        float g = accg[rf][c][jj];
        float hm = g / (1.f + __expf(-g)) * accu[rf][c][jj];
        tbuf[row * 72 + col] = f2bf(hm);
      }
  __syncthreads();
  #pragma unroll
  for (int p = 0; p < 2; ++p) {
    const int row = (tid >> 2) + p * 128, cs = tid & 3;
    if (row < cntb) {
      short8 v0 = *(const short8*)&tbuf[row * 72 + cs * 16];
      short8 v1 = *(const short8*)&tbuf[row * 72 + cs * 16 + 8];
      ushort* dst = hmid + (size_t)(start + tokbase + row) * I_DIM + i0 + cs * 16;
      *(short8*)dst = v0;
      *(short8*)(dst + 8) = v1;
    }
  }
}

// ---------------- K2: fused fp32-weight down-proj -> out_pairs (bf16) ------
#define K2_TB 256
#define KC2 128
#define DS_ST 138
__global__ __launch_bounds__(512) void k2_down(const ushort* __restrict__ hmid,
                                               const float* __restrict__ wd,
                                               const int* __restrict__ offsets,
                                               ushort* __restrict__ out_pairs) {
  const int e = blockIdx.y, hs = blockIdx.x;
  const int h0 = hs * 192;
  const int start = offsets[e], cnt = offsets[e + 1] - start;
  const int tokbase = blockIdx.z * K2_TB;
  if (tokbase >= cnt) return;
  const int tm = min(K2_TB, cnt - tokbase);

  __shared__ ushort Ds[192][DS_ST];

  const int tid = threadIdx.x, l = tid & 63, wid = tid >> 6;
  const int tf = wid & 3, ch = wid >> 2;
  const int la15 = l & 15;
  const int ko = (l >> 4) * 8;
  f32x4 acc[4][6] = {};

  int p[4];
  #pragma unroll
  for (int rf = 0; rf < 4; ++rf)
    p[rf] = min(start + tokbase + tf * 64 + rf * 16 + la15, NPAIR - 1);

  const float* wde = wd + (size_t)e * I_DIM * H_DIM;

  for (int kh = 0; kh < I_DIM; kh += KC2) {
    __syncthreads();
    #pragma unroll
    for (int it = 0; it < 6; ++it) {
      int idx = tid + it * 512;
      int qq = idx % 48, m = idx / 48;
      const int k0 = 2 * m;
      const float* src = wde + (size_t)(kh + k0) * H_DIM + h0 + qq * 4;
      float4 v0 = *(const float4*)src;
      float4 v1 = *(const float4*)(src + H_DIM);
      *(unsigned*)&Ds[qq * 4 + 0][k0] = pack2(v0.x, v1.x);
      *(unsigned*)&Ds[qq * 4 + 1][k0] = pack2(v0.y, v1.y);
      *(unsigned*)&Ds[qq * 4 + 2][k0] = pack2(v0.z, v1.z);
      *(unsigned*)&Ds[qq * 4 + 3][k0] = pack2(v0.w, v1.w);
    }
    __syncthreads();
    #pragma unroll
    for (int ks = 0; ks < 4; ++ks) {
      const int kof = ks * 32 + ko;
      short8 a[4];
      #pragma unroll
      for (int rf = 0; rf < 4; ++rf)
        a[rf] = *(const short8*)(hmid + (size_t)p[rf] * I_DIM + kh + kof);
      __builtin_amdgcn_s_setprio(1);
      #pragma unroll
      for (int cf = 0; cf < 6; ++cf) {
        short8 b = *(const short8*)&Ds[ch * 96 + cf * 16 + la15][kof];
        #pragma unroll
        for (int rf = 0; rf < 4; ++rf)
          acc[rf][cf] = mfma16(a[rf], b, acc[rf][cf]);
      }
      __builtin_amdgcn_s_setprio(0);
    }
  }

  const int rgrp = l >> 4;
  #pragma unroll
  for (int rf = 0; rf < 4; ++rf)
    #pragma unroll
    for (int jj = 0; jj < 4; ++jj) {
      int r = tf * 64 + rf * 16 + rgrp * 4 + jj;
      if (r < tm) {
        const size_t prow = (size_t)(start + tokbase + r);
        #pragma unroll
        for (int cf = 0; cf < 6; ++cf) {
          int hcol = h0 + ch * 96 + cf * 16 + la15;
          out_pairs[prow * H_DIM + hcol] = f2bf(acc[rf][cf][jj]);
        }
      }
    }
}

// ---------------- Gather-reduce: out[t] = sum_k w_k * out_pairs_bf[pos] ----
__global__ __launch_bounds__(192) void moe_reduce(const ushort* __restrict__ out_pairs,
                                                  const int* __restrict__ pairpos,
                                                  const float* __restrict__ topw,
                                                  float* __restrict__ out) {
  const int t = blockIdx.x;
  const int c = threadIdx.x;  // 0..191, 4 bf16 per thread
  float4 acc = make_float4(0.f, 0.f, 0.f, 0.f);
  #pragma unroll
  for (int k = 0; k < TOPK; ++k) {
    const int pos = pairpos[t * TOPK + k];
    const float w = topw[t * TOPK + k];
    short4v v = *(const short4v*)&out_pairs[(size_t)pos * H_DIM + c * 4];
    acc.x = fmaf(w, bf2f((ushort)v[0]), acc.x);
    acc.y = fmaf(w, bf2f((ushort)v[1]), acc.y);
    acc.z = fmaf(w, bf2f((ushort)v[2]), acc.z);
    acc.w = fmaf(w, bf2f((ushort)v[3]), acc.w);
  }
  *(float4*)&out[(size_t)t * H_DIM + c * 4] = acc;
}

extern "C" void kernel_launch(void* const* d_in, const int* in_sizes, int n_in,
                              void* d_out, int out_size, void* d_ws, size_t ws_size,
                              hipStream_t stream) {
  const float* x  = (const float*)d_in[0];
  const float* rw = (const float*)d_in[1];
  const float* wg = (const float*)d_in[2];
  const float* wu = (const float*)d_in[3];
  const float* wd = (const float*)d_in[4];
  float* out = (float*)d_out;

  char* ws = (char*)d_ws;
  int*    topi     = (int*)(ws + 0);
  float*  topw     = (float*)(ws + 65536);
  int*    offsets  = (int*)(ws + 131072);
  int*    toklist  = (int*)(ws + 132608);
  int*    pairpos  = (int*)(ws + 264192);
  ushort* xbf      = (ushort*)(ws + 331776);   // 3 MB
  ushort* hmid     = (ushort*)(ws + 3477504);  // 8 MB
  float*  rpart    = (float*)(ws + 3477504);   // overlaps hmid; dead before k1
  ushort* out_pairs= (ushort*)(ws + 11866112); // 25.2 MB bf16 -> ends ~37 MB

  cvt_x_kernel<<<(N_TOK * H_DIM / 8) / 512, 512, 0, stream>>>(x, xbf);
  router_gemm<<<dim3(N_TOK / 64, 3), 256, 0, stream>>>(x, rw, rpart);
  router_topk<<<N_TOK / 4, 256, 0, stream>>>(rpart, topi, topw);
  hist_prefix_kernel<<<1, 256, 0, stream>>>(topi, offsets);
  scatter64<<<E_NUM, 256, 0, stream>>>(topi, offsets, toklist, pairpos);
  // z-grids cover worst-case cnt == 2048: ceil(2048/192)=11, ceil(2048/256)=8
  k1_gateup<<<dim3(4, E_NUM, 11), 512, 0, stream>>>(xbf, wg, wu, offsets, toklist, hmid);
  k2_down<<<dim3(4, E_NUM, 8), 512, 0, stream>>>(hmid, wd, offsets, out_pairs);
  moe_reduce<<<N_TOK, 192, 0, stream>>>(out_pairs, pairpos, topw, out);
}